// Round 2
// baseline (3186.956 us; speedup 1.0000x reference)
//
#include <hip/hip_runtime.h>
#include <hip/hip_bf16.h>

#define N_NODES 10000
#define N_EDGES 160000
#define FEAT 512
#define D 128
#define NRBF 20
#define RCUT 1.4415f

__device__ __forceinline__ float silu_f(float x) { return x / (1.0f + __expf(-x)); }

// ---------------------------------------------------------------- K0: init
// xacc (= d_out) <- x ; xacc2 (= ws) <- 0    (ws is poisoned 0xAA every call)
__global__ __launch_bounds__(256) void k_init(const float4* __restrict__ x,
                                              float4* __restrict__ xacc,
                                              float4* __restrict__ xacc2) {
    int i = blockIdx.x * blockDim.x + threadIdx.x;
    if (i < N_NODES * FEAT / 4) {
        xacc[i]  = x[i];
        xacc2[i] = make_float4(0.f, 0.f, 0.f, 0.f);
    }
}

// ---------------------------------------------------------------- K1: phase 1
#define EPB1 16
__global__ __launch_bounds__(256) void k_phase1(
    const float* __restrict__ x,
    const int* __restrict__ ei,
    const float* __restrict__ ea1,
    const float* __restrict__ ea2,
    const float* __restrict__ W1, const float* __restrict__ b1,
    const float* __restrict__ W2, const float* __restrict__ b2,
    const float* __restrict__ W3, const float* __restrict__ b3,
    float* __restrict__ xacc)
{
    __shared__ float sj[EPB1][D];        // gathered scalar features
    __shared__ float tt[EPB1][D];        // silu(sj@W1+b1)
    __shared__ float basis[EPB1][NRBF];  // rbf*cutoff
    __shared__ float eal[EPB1][3];
    __shared__ int srcl[EPB1], dstl[EPB1];

    const int t = threadIdx.x;
    const int j = t & 127;      // feature column
    const int grp = t >> 7;     // 0/1, each handles 8 edges
    const int e0 = blockIdx.x * EPB1;

    if (t < EPB1) { srcl[t] = ei[e0 + t]; dstl[t] = ei[N_EDGES + e0 + t]; }
    if (t >= 64 && t < 64 + EPB1 * 3) {
        int i2 = t - 64;
        eal[i2 / 3][i2 % 3] = ea1[(e0 + i2 / 3) * 3 + (i2 % 3)];
    }
    __syncthreads();

    // gather s_j (cols 384..511) for this grp's 8 edges
    #pragma unroll
    for (int e = 0; e < 8; ++e) {
        int ee = grp * 8 + e;
        sj[ee][j] = x[(long)srcl[ee] * FEAT + 384 + j];
    }
    // rbf basis: 16 edges x 20
    for (int i = t; i < EPB1 * NRBF; i += 256) {
        int e = i / NRBF, n = i % NRBF;
        float r  = ea2[e0 + e];
        float pr = 3.14159265358979f * r / RCUT;
        float rbf = sqrtf(2.0f / RCUT) * sinf((float)(n + 1) * pr) / r;
        float cut = 0.5f * (cosf(pr) + 1.0f) * (r < RCUT ? 1.0f : 0.0f);
        basis[e][n] = rbf * cut;
    }
    __syncthreads();

    // T = silu(sj @ W1 + b1)   (16x128)
    {
        float b1k = b1[j];
        float acc[8];
        #pragma unroll
        for (int e = 0; e < 8; ++e) acc[e] = b1k;
        for (int jj = 0; jj < D; ++jj) {
            float w = W1[jj * D + j];
            #pragma unroll
            for (int e = 0; e < 8; ++e) acc[e] += sj[grp * 8 + e][jj] * w;
        }
        #pragma unroll
        for (int e = 0; e < 8; ++e) tt[grp * 8 + e][j] = silu_f(acc[e]);
    }
    __syncthreads();

    // split = (T@W3 + b3) * (basis@W2 + b2);  sp[c3][e] = split[:, c3*128 + j]
    float sp[3][8];
    #pragma unroll
    for (int c3 = 0; c3 < 3; ++c3) {
        const int k2 = c3 * D + j;
        float accf[8], accb[8];
        float b3k = b3[k2];
        float b2k = b2[k2];
        #pragma unroll
        for (int e = 0; e < 8; ++e) { accf[e] = b3k; accb[e] = b2k; }
        for (int jj = 0; jj < D; ++jj) {
            float w = W3[jj * 384 + k2];
            #pragma unroll
            for (int e = 0; e < 8; ++e) accf[e] += tt[grp * 8 + e][jj] * w;
        }
        for (int n = 0; n < NRBF; ++n) {
            float w = W2[n * 384 + k2];
            #pragma unroll
            for (int e = 0; e < 8; ++e) accb[e] += basis[grp * 8 + e][n] * w;
        }
        #pragma unroll
        for (int e = 0; e < 8; ++e) sp[c3][e] = accf[e] * accb[e];
    }

    // message scatter: v_msg = v_j*s1 + s3*ea1 (cols 3j..3j+2), s2 (col 384+j)
    #pragma unroll
    for (int e = 0; e < 8; ++e) {
        int ee = grp * 8 + e;
        int src = srcl[ee], dst = dstl[ee];
        float s1v = sp[0][e], s2v = sp[1][e], s3v = sp[2][e];
        float* xd = xacc + (long)dst * FEAT;
        #pragma unroll
        for (int c = 0; c < 3; ++c) {
            float vj = x[(long)src * FEAT + j * 3 + c];
            atomicAdd(xd + j * 3 + c, vj * s1v + s3v * eal[ee][c]);
        }
        atomicAdd(xd + 384 + j, s2v);
    }
}

// ---------------------------------------------------------------- K2: phase 2
#define EPB2 8
__global__ __launch_bounds__(256) void k_phase2(
    const int* __restrict__ ei,
    const float* __restrict__ U,
    const float* __restrict__ V,
    const float* __restrict__ Wu1, const float* __restrict__ bu1,
    const float* __restrict__ Wu2, const float* __restrict__ bu2,
    const float* __restrict__ xacc, float* __restrict__ xacc2)
{
    __shared__ float xj[EPB2][FEAT];   // 16KB gathered post-phase1 rows
    __shared__ float vu[EPB2][384];    // 12KB  (v@U), (3,128) row-major flat
    __shared__ float vv[EPB2][384];    // 12KB  (v@U@V)
    __shared__ float nrm[EPB2][D];     // 4KB
    __shared__ float h1[EPB2][D];      // 4KB
    __shared__ int srcl[EPB2], dstl[EPB2];

    const int t = threadIdx.x;
    const int j = t & 127;
    const int grp = t >> 7;  // 0/1, each handles 4 edges
    const int e0 = blockIdx.x * EPB2;

    if (t < EPB2) { srcl[t] = ei[e0 + t]; dstl[t] = ei[N_EDGES + e0 + t]; }
    __syncthreads();
    for (int i = t; i < EPB2 * FEAT; i += 256) {
        int e = i >> 9, f = i & 511;
        xj[e][f] = xacc[(long)srcl[e] * FEAT + f];
    }
    __syncthreads();

    // vu[e][r*128+k] = sum_jj xj[e][r*128+jj] * U[jj][k]   ((3,128) view)
    {
        float acc[12];
        #pragma unroll
        for (int i = 0; i < 12; ++i) acc[i] = 0.0f;
        for (int jj = 0; jj < D; ++jj) {
            float u = U[jj * D + j];
            #pragma unroll
            for (int e = 0; e < 4; ++e)
                #pragma unroll
                for (int r = 0; r < 3; ++r)
                    acc[e * 3 + r] += xj[grp * 4 + e][r * D + jj] * u;
        }
        #pragma unroll
        for (int e = 0; e < 4; ++e)
            #pragma unroll
            for (int r = 0; r < 3; ++r)
                vu[grp * 4 + e][r * D + j] = acc[e * 3 + r];
    }
    __syncthreads();

    // vv = vu @ V
    {
        float acc[12];
        #pragma unroll
        for (int i = 0; i < 12; ++i) acc[i] = 0.0f;
        for (int jj = 0; jj < D; ++jj) {
            float v = V[jj * D + j];
            #pragma unroll
            for (int e = 0; e < 4; ++e)
                #pragma unroll
                for (int r = 0; r < 3; ++r)
                    acc[e * 3 + r] += vu[grp * 4 + e][r * D + jj] * v;
        }
        #pragma unroll
        for (int e = 0; e < 4; ++e)
            #pragma unroll
            for (int r = 0; r < 3; ++r)
                vv[grp * 4 + e][r * D + j] = acc[e * 3 + r];
    }
    __syncthreads();

    // norm over the (128,3) view: nrm[e][j] = ||vv[e][3j..3j+2]||
    #pragma unroll
    for (int e = 0; e < 4; ++e) {
        int ee = grp * 4 + e;
        float a = vv[ee][3 * j], b = vv[ee][3 * j + 1], c = vv[ee][3 * j + 2];
        nrm[ee][j] = sqrtf(a * a + b * b + c * c);
    }
    __syncthreads();

    // h1 = silu([norm, s] @ Wu1 + bu1)
    {
        float acc[4];
        float bk = bu1[j];
        #pragma unroll
        for (int e = 0; e < 4; ++e) acc[e] = bk;
        for (int jj = 0; jj < D; ++jj) {
            float wa = Wu1[jj * D + j];
            #pragma unroll
            for (int e = 0; e < 4; ++e) acc[e] += nrm[grp * 4 + e][jj] * wa;
        }
        for (int jj = 0; jj < D; ++jj) {
            float wb = Wu1[(D + jj) * D + j];
            #pragma unroll
            for (int e = 0; e < 4; ++e) acc[e] += xj[grp * 4 + e][384 + jj] * wb;
        }
        #pragma unroll
        for (int e = 0; e < 4; ++e) h1[grp * 4 + e][j] = silu_f(acc[e]);
    }
    __syncthreads();

    // h = h1 @ Wu2 + bu2; need only s1 (cols 0..127) and s3 (cols 256..383)
    {
        float a1[4], a3[4];
        float bs1 = bu2[j], bs3 = bu2[256 + j];
        #pragma unroll
        for (int e = 0; e < 4; ++e) { a1[e] = bs1; a3[e] = bs3; }
        for (int jj = 0; jj < D; ++jj) {
            float w1 = Wu2[jj * 384 + j];
            float w3 = Wu2[jj * 384 + 256 + j];
            #pragma unroll
            for (int e = 0; e < 4; ++e) {
                float h = h1[grp * 4 + e][jj];
                a1[e] += h * w1;
                a3[e] += h * w3;
            }
        }
        #pragma unroll
        for (int e = 0; e < 4; ++e) {
            int ee = grp * 4 + e;
            int dst = dstl[ee];
            float* xd = xacc2 + (long)dst * FEAT;
            float dot = 0.0f;
            #pragma unroll
            for (int c = 0; c < 3; ++c) {
                float vf = vu[ee][3 * j + c] * a1[e];
                dot += vf * vv[ee][3 * j + c];
                atomicAdd(xd + 3 * j + c, vf);
            }
            atomicAdd(xd + 384 + j, dot + a3[e]);
        }
    }
}

// ---------------------------------------------------------------- K3: combine (in-place into out)
__global__ __launch_bounds__(256) void k_final(float4* __restrict__ out,
                                               const float4* __restrict__ xacc2) {
    int i = blockIdx.x * blockDim.x + threadIdx.x;
    if (i < N_NODES * FEAT / 4) {
        float4 a = out[i], b = xacc2[i];
        out[i] = make_float4(a.x + b.x, a.y + b.y, a.z + b.z, a.w + b.w);
    }
}

extern "C" void kernel_launch(void* const* d_in, const int* in_sizes, int n_in,
                              void* d_out, int out_size, void* d_ws, size_t ws_size,
                              hipStream_t stream) {
    (void)in_sizes; (void)n_in; (void)out_size; (void)ws_size;
    const float* x   = (const float*)d_in[0];
    const int*   ei  = (const int*)d_in[1];
    const float* ea1 = (const float*)d_in[2];
    const float* ea2 = (const float*)d_in[3];
    const float* W1  = (const float*)d_in[4];
    const float* b1  = (const float*)d_in[5];
    const float* W2  = (const float*)d_in[6];
    const float* b2  = (const float*)d_in[7];
    const float* W3  = (const float*)d_in[8];
    const float* b3  = (const float*)d_in[9];
    const float* U   = (const float*)d_in[10];
    const float* V   = (const float*)d_in[11];
    const float* Wu1 = (const float*)d_in[12];
    const float* bu1 = (const float*)d_in[13];
    const float* Wu2 = (const float*)d_in[14];
    const float* bu2 = (const float*)d_in[15];

    float* xacc  = (float*)d_out;   // N*512 fp32: x + phase1 messages (is the output base)
    float* xacc2 = (float*)d_ws;    // N*512 fp32: phase2 messages

    const int NV4 = N_NODES * FEAT / 4;
    k_init  <<<(NV4 + 255) / 256, 256, 0, stream>>>((const float4*)x, (float4*)xacc, (float4*)xacc2);
    k_phase1<<<N_EDGES / EPB1,    256, 0, stream>>>(x, ei, ea1, ea2, W1, b1, W2, b2, W3, b3, xacc);
    k_phase2<<<N_EDGES / EPB2,    256, 0, stream>>>(ei, U, V, Wu1, bu1, Wu2, bu2, xacc, xacc2);
    k_final <<<(NV4 + 255) / 256, 256, 0, stream>>>((float4*)xacc, (const float4*)xacc2);
}

// Round 3
// 3004.622 us; speedup vs baseline: 1.0607x; 1.0607x over previous
//
#include <hip/hip_runtime.h>
#include <hip/hip_bf16.h>

#define N_NODES 10000
#define N_EDGES 160000
#define FEAT 512
#define D 128
#define NRBF 20
#define RCUT 1.4415f

__device__ __forceinline__ float silu_f(float x) { return x / (1.0f + __expf(-x)); }

// ================================================================= CSR build
__global__ __launch_bounds__(256) void k_zero_ints(int* __restrict__ p, int n) {
    int i = blockIdx.x * blockDim.x + threadIdx.x;
    if (i < n) p[i] = 0;
}

__global__ __launch_bounds__(256) void k_count(const int* __restrict__ ei,
                                               int* __restrict__ count) {
    int e = blockIdx.x * blockDim.x + threadIdx.x;
    if (e < N_EDGES) atomicAdd(&count[ei[N_EDGES + e]], 1);
}

// single block, 256 threads, chunk=40 -> exclusive prefix over 10000 nodes
__global__ __launch_bounds__(256) void k_scan(const int* __restrict__ count,
                                              int* __restrict__ offsets) {
    __shared__ int sums[256];
    const int t = threadIdx.x;
    const int base = t * 40;
    int s = 0;
    for (int i = 0; i < 40; ++i) {
        int idx = base + i;
        if (idx < N_NODES) s += count[idx];
    }
    sums[t] = s;
    __syncthreads();
    for (int off = 1; off < 256; off <<= 1) {
        int v = (t >= off) ? sums[t - off] : 0;
        __syncthreads();
        sums[t] += v;
        __syncthreads();
    }
    int run = (t == 0) ? 0 : sums[t - 1];
    for (int i = 0; i < 40; ++i) {
        int idx = base + i;
        if (idx < N_NODES) { offsets[idx] = run; run += count[idx]; }
    }
    if (t == 255) offsets[N_NODES] = run;
}

__global__ __launch_bounds__(256) void k_bin(const int* __restrict__ ei,
                                             const int* __restrict__ offsets,
                                             int* __restrict__ cursor,
                                             int* __restrict__ bucket) {
    int e = blockIdx.x * blockDim.x + threadIdx.x;
    if (e < N_EDGES) {
        int d = ei[N_EDGES + e];
        int pos = offsets[d] + atomicAdd(&cursor[d], 1);
        bucket[pos] = e;
    }
}

// ============================================================ phase-1 message
// msg[e] layout (bf16, 512): [c*128+j] = v_msg[j][c] for c<3, [384+j] = s2[j]
#define EPB1 16
__global__ __launch_bounds__(256) void k_p1msg(
    const float* __restrict__ x,
    const int* __restrict__ ei,
    const float* __restrict__ ea1,
    const float* __restrict__ ea2,
    const float* __restrict__ W1, const float* __restrict__ b1,
    const float* __restrict__ W2, const float* __restrict__ b2,
    const float* __restrict__ W3, const float* __restrict__ b3,
    __hip_bfloat16* __restrict__ msg)
{
    __shared__ float sj[EPB1][D];
    __shared__ float tt[EPB1][D];
    __shared__ float basis[EPB1][NRBF];
    __shared__ float eal[EPB1][3];
    __shared__ int srcl[EPB1];

    const int t = threadIdx.x;
    const int j = t & 127;
    const int grp = t >> 7;
    const int e0 = blockIdx.x * EPB1;

    if (t < EPB1) srcl[t] = ei[e0 + t];
    if (t >= 64 && t < 64 + EPB1 * 3) {
        int i2 = t - 64;
        eal[i2 / 3][i2 % 3] = ea1[(e0 + i2 / 3) * 3 + (i2 % 3)];
    }
    __syncthreads();

    #pragma unroll
    for (int e = 0; e < 8; ++e) {
        int ee = grp * 8 + e;
        sj[ee][j] = x[(size_t)srcl[ee] * FEAT + 384 + j];
    }
    for (int i = t; i < EPB1 * NRBF; i += 256) {
        int e = i / NRBF, n = i % NRBF;
        float r  = ea2[e0 + e];
        float pr = 3.14159265358979f * r / RCUT;
        float rbf = sqrtf(2.0f / RCUT) * sinf((float)(n + 1) * pr) / r;
        float cut = 0.5f * (cosf(pr) + 1.0f) * (r < RCUT ? 1.0f : 0.0f);
        basis[e][n] = rbf * cut;
    }
    __syncthreads();

    // T = silu(sj @ W1 + b1)
    {
        float b1k = b1[j];
        float acc[8];
        #pragma unroll
        for (int e = 0; e < 8; ++e) acc[e] = b1k;
        for (int jj = 0; jj < D; ++jj) {
            float w = W1[jj * D + j];
            #pragma unroll
            for (int e = 0; e < 8; ++e) acc[e] += sj[grp * 8 + e][jj] * w;
        }
        #pragma unroll
        for (int e = 0; e < 8; ++e) tt[grp * 8 + e][j] = silu_f(acc[e]);
    }
    __syncthreads();

    // split = (T@W3 + b3) * (basis@W2 + b2)
    float sp[3][8];
    #pragma unroll
    for (int c3 = 0; c3 < 3; ++c3) {
        const int k2 = c3 * D + j;
        float accf[8], accb[8];
        float b3k = b3[k2];
        float b2k = b2[k2];
        #pragma unroll
        for (int e = 0; e < 8; ++e) { accf[e] = b3k; accb[e] = b2k; }
        for (int jj = 0; jj < D; ++jj) {
            float w = W3[jj * 384 + k2];
            #pragma unroll
            for (int e = 0; e < 8; ++e) accf[e] += tt[grp * 8 + e][jj] * w;
        }
        for (int n = 0; n < NRBF; ++n) {
            float w = W2[n * 384 + k2];
            #pragma unroll
            for (int e = 0; e < 8; ++e) accb[e] += basis[grp * 8 + e][n] * w;
        }
        #pragma unroll
        for (int e = 0; e < 8; ++e) sp[c3][e] = accf[e] * accb[e];
    }

    // write messages (coalesced bf16 stores, no atomics)
    #pragma unroll
    for (int e = 0; e < 8; ++e) {
        int ee = grp * 8 + e;
        int src = srcl[ee];
        __hip_bfloat16* mrow = msg + (size_t)(e0 + ee) * FEAT;
        float s1v = sp[0][e], s2v = sp[1][e], s3v = sp[2][e];
        #pragma unroll
        for (int c = 0; c < 3; ++c) {
            float vj = x[(size_t)src * FEAT + 3 * j + c];
            mrow[c * 128 + j] = __float2bfloat16(vj * s1v + s3v * eal[ee][c]);
        }
        mrow[384 + j] = __float2bfloat16(s2v);
    }
}

// ============================================================ phase-2 message
#define EPB2 8
__global__ __launch_bounds__(256) void k_p2msg(
    const int* __restrict__ ei,
    const float* __restrict__ U,
    const float* __restrict__ V,
    const float* __restrict__ Wu1, const float* __restrict__ bu1,
    const float* __restrict__ Wu2, const float* __restrict__ bu2,
    const float* __restrict__ xacc,
    __hip_bfloat16* __restrict__ msg)
{
    __shared__ float xj[EPB2][FEAT];
    __shared__ float vu[EPB2][384];
    __shared__ float vv[EPB2][384];
    __shared__ float nrm[EPB2][D];
    __shared__ float h1[EPB2][D];
    __shared__ int srcl[EPB2];

    const int t = threadIdx.x;
    const int j = t & 127;
    const int grp = t >> 7;
    const int e0 = blockIdx.x * EPB2;

    if (t < EPB2) srcl[t] = ei[e0 + t];
    __syncthreads();
    for (int i = t; i < EPB2 * FEAT; i += 256) {
        int e = i >> 9, f = i & 511;
        xj[e][f] = xacc[(size_t)srcl[e] * FEAT + f];
    }
    __syncthreads();

    // vu = (3,128) view of xj[:384] @ U
    {
        float acc[12];
        #pragma unroll
        for (int i = 0; i < 12; ++i) acc[i] = 0.0f;
        for (int jj = 0; jj < D; ++jj) {
            float u = U[jj * D + j];
            #pragma unroll
            for (int e = 0; e < 4; ++e)
                #pragma unroll
                for (int r = 0; r < 3; ++r)
                    acc[e * 3 + r] += xj[grp * 4 + e][r * D + jj] * u;
        }
        #pragma unroll
        for (int e = 0; e < 4; ++e)
            #pragma unroll
            for (int r = 0; r < 3; ++r)
                vu[grp * 4 + e][r * D + j] = acc[e * 3 + r];
    }
    __syncthreads();

    // vv = vu @ V
    {
        float acc[12];
        #pragma unroll
        for (int i = 0; i < 12; ++i) acc[i] = 0.0f;
        for (int jj = 0; jj < D; ++jj) {
            float v = V[jj * D + j];
            #pragma unroll
            for (int e = 0; e < 4; ++e)
                #pragma unroll
                for (int r = 0; r < 3; ++r)
                    acc[e * 3 + r] += vu[grp * 4 + e][r * D + jj] * v;
        }
        #pragma unroll
        for (int e = 0; e < 4; ++e)
            #pragma unroll
            for (int r = 0; r < 3; ++r)
                vv[grp * 4 + e][r * D + j] = acc[e * 3 + r];
    }
    __syncthreads();

    #pragma unroll
    for (int e = 0; e < 4; ++e) {
        int ee = grp * 4 + e;
        float a = vv[ee][3 * j], b = vv[ee][3 * j + 1], c = vv[ee][3 * j + 2];
        nrm[ee][j] = sqrtf(a * a + b * b + c * c);
    }
    __syncthreads();

    // h1 = silu([norm, s] @ Wu1 + bu1)
    {
        float acc[4];
        float bk = bu1[j];
        #pragma unroll
        for (int e = 0; e < 4; ++e) acc[e] = bk;
        for (int jj = 0; jj < D; ++jj) {
            float wa = Wu1[jj * D + j];
            #pragma unroll
            for (int e = 0; e < 4; ++e) acc[e] += nrm[grp * 4 + e][jj] * wa;
        }
        for (int jj = 0; jj < D; ++jj) {
            float wb = Wu1[(D + jj) * D + j];
            #pragma unroll
            for (int e = 0; e < 4; ++e) acc[e] += xj[grp * 4 + e][384 + jj] * wb;
        }
        #pragma unroll
        for (int e = 0; e < 4; ++e) h1[grp * 4 + e][j] = silu_f(acc[e]);
    }
    __syncthreads();

    // h = h1 @ Wu2 + bu2 (only s1, s3 needed); write messages
    {
        float a1[4], a3[4];
        float bs1 = bu2[j], bs3 = bu2[256 + j];
        #pragma unroll
        for (int e = 0; e < 4; ++e) { a1[e] = bs1; a3[e] = bs3; }
        for (int jj = 0; jj < D; ++jj) {
            float w1 = Wu2[jj * 384 + j];
            float w3 = Wu2[jj * 384 + 256 + j];
            #pragma unroll
            for (int e = 0; e < 4; ++e) {
                float h = h1[grp * 4 + e][jj];
                a1[e] += h * w1;
                a3[e] += h * w3;
            }
        }
        #pragma unroll
        for (int e = 0; e < 4; ++e) {
            int ee = grp * 4 + e;
            __hip_bfloat16* mrow = msg + (size_t)(e0 + ee) * FEAT;
            float dot = 0.0f;
            #pragma unroll
            for (int c = 0; c < 3; ++c) {
                float vf = vu[ee][3 * j + c] * a1[e];
                dot += vf * vv[ee][3 * j + c];
                mrow[c * 128 + j] = __float2bfloat16(vf);
            }
            mrow[384 + j] = __float2bfloat16(dot + a3[e]);
        }
    }
}

// ================================================================== gather
// out[d][g] = base[d][g] + sum_{e in CSR[d]} msg[e][perm(g)]
__global__ __launch_bounds__(256) void k_gather(
    const __hip_bfloat16* __restrict__ msg,
    const int* __restrict__ offsets,
    const int* __restrict__ bucket,
    const float* __restrict__ base,
    float* __restrict__ out)
{
    __shared__ float row[FEAT];
    const int d = blockIdx.x, t = threadIdx.x;
    const int o0 = offsets[d], o1 = offsets[d + 1];
    float a0 = 0.0f, a1 = 0.0f;
    for (int i = o0; i < o1; ++i) {
        int e = bucket[i];
        const __hip_bfloat162* r = (const __hip_bfloat162*)(msg + (size_t)e * FEAT);
        __hip_bfloat162 v = r[t];
        a0 += __bfloat162float(v.x);
        a1 += __bfloat162float(v.y);
    }
    row[2 * t]     = a0;
    row[2 * t + 1] = a1;
    __syncthreads();
    #pragma unroll
    for (int gi = 0; gi < 2; ++gi) {
        int g = t + gi * 256;
        int m = (g < 384) ? ((g % 3) * 128 + g / 3) : g;
        out[(size_t)d * FEAT + g] = base[(size_t)d * FEAT + g] + row[m];
    }
}

// ====================== fallback path (round-2 atomic version, ws >= 21 MB) ==
__global__ __launch_bounds__(256) void k_init(const float4* __restrict__ x,
                                              float4* __restrict__ xacc,
                                              float4* __restrict__ xacc2) {
    int i = blockIdx.x * blockDim.x + threadIdx.x;
    if (i < N_NODES * FEAT / 4) {
        xacc[i]  = x[i];
        xacc2[i] = make_float4(0.f, 0.f, 0.f, 0.f);
    }
}

__global__ __launch_bounds__(256) void k_phase1_atomic(
    const float* __restrict__ x, const int* __restrict__ ei,
    const float* __restrict__ ea1, const float* __restrict__ ea2,
    const float* __restrict__ W1, const float* __restrict__ b1,
    const float* __restrict__ W2, const float* __restrict__ b2,
    const float* __restrict__ W3, const float* __restrict__ b3,
    float* __restrict__ xacc)
{
    __shared__ float sj[EPB1][D];
    __shared__ float tt[EPB1][D];
    __shared__ float basis[EPB1][NRBF];
    __shared__ float eal[EPB1][3];
    __shared__ int srcl[EPB1], dstl[EPB1];
    const int t = threadIdx.x;
    const int j = t & 127;
    const int grp = t >> 7;
    const int e0 = blockIdx.x * EPB1;
    if (t < EPB1) { srcl[t] = ei[e0 + t]; dstl[t] = ei[N_EDGES + e0 + t]; }
    if (t >= 64 && t < 64 + EPB1 * 3) {
        int i2 = t - 64;
        eal[i2 / 3][i2 % 3] = ea1[(e0 + i2 / 3) * 3 + (i2 % 3)];
    }
    __syncthreads();
    #pragma unroll
    for (int e = 0; e < 8; ++e) {
        int ee = grp * 8 + e;
        sj[ee][j] = x[(size_t)srcl[ee] * FEAT + 384 + j];
    }
    for (int i = t; i < EPB1 * NRBF; i += 256) {
        int e = i / NRBF, n = i % NRBF;
        float r  = ea2[e0 + e];
        float pr = 3.14159265358979f * r / RCUT;
        float rbf = sqrtf(2.0f / RCUT) * sinf((float)(n + 1) * pr) / r;
        float cut = 0.5f * (cosf(pr) + 1.0f) * (r < RCUT ? 1.0f : 0.0f);
        basis[e][n] = rbf * cut;
    }
    __syncthreads();
    {
        float b1k = b1[j];
        float acc[8];
        #pragma unroll
        for (int e = 0; e < 8; ++e) acc[e] = b1k;
        for (int jj = 0; jj < D; ++jj) {
            float w = W1[jj * D + j];
            #pragma unroll
            for (int e = 0; e < 8; ++e) acc[e] += sj[grp * 8 + e][jj] * w;
        }
        #pragma unroll
        for (int e = 0; e < 8; ++e) tt[grp * 8 + e][j] = silu_f(acc[e]);
    }
    __syncthreads();
    float sp[3][8];
    #pragma unroll
    for (int c3 = 0; c3 < 3; ++c3) {
        const int k2 = c3 * D + j;
        float accf[8], accb[8];
        float b3k = b3[k2];
        float b2k = b2[k2];
        #pragma unroll
        for (int e = 0; e < 8; ++e) { accf[e] = b3k; accb[e] = b2k; }
        for (int jj = 0; jj < D; ++jj) {
            float w = W3[jj * 384 + k2];
            #pragma unroll
            for (int e = 0; e < 8; ++e) accf[e] += tt[grp * 8 + e][jj] * w;
        }
        for (int n = 0; n < NRBF; ++n) {
            float w = W2[n * 384 + k2];
            #pragma unroll
            for (int e = 0; e < 8; ++e) accb[e] += basis[grp * 8 + e][n] * w;
        }
        #pragma unroll
        for (int e = 0; e < 8; ++e) sp[c3][e] = accf[e] * accb[e];
    }
    #pragma unroll
    for (int e = 0; e < 8; ++e) {
        int ee = grp * 8 + e;
        int src = srcl[ee], dst = dstl[ee];
        float s1v = sp[0][e], s2v = sp[1][e], s3v = sp[2][e];
        float* xd = xacc + (size_t)dst * FEAT;
        #pragma unroll
        for (int c = 0; c < 3; ++c) {
            float vj = x[(size_t)src * FEAT + j * 3 + c];
            atomicAdd(xd + j * 3 + c, vj * s1v + s3v * eal[ee][c]);
        }
        atomicAdd(xd + 384 + j, s2v);
    }
}

__global__ __launch_bounds__(256) void k_phase2_atomic(
    const int* __restrict__ ei,
    const float* __restrict__ U, const float* __restrict__ V,
    const float* __restrict__ Wu1, const float* __restrict__ bu1,
    const float* __restrict__ Wu2, const float* __restrict__ bu2,
    const float* __restrict__ xacc, float* __restrict__ xacc2)
{
    __shared__ float xj[EPB2][FEAT];
    __shared__ float vu[EPB2][384];
    __shared__ float vv[EPB2][384];
    __shared__ float nrm[EPB2][D];
    __shared__ float h1[EPB2][D];
    __shared__ int srcl[EPB2], dstl[EPB2];
    const int t = threadIdx.x;
    const int j = t & 127;
    const int grp = t >> 7;
    const int e0 = blockIdx.x * EPB2;
    if (t < EPB2) { srcl[t] = ei[e0 + t]; dstl[t] = ei[N_EDGES + e0 + t]; }
    __syncthreads();
    for (int i = t; i < EPB2 * FEAT; i += 256) {
        int e = i >> 9, f = i & 511;
        xj[e][f] = xacc[(size_t)srcl[e] * FEAT + f];
    }
    __syncthreads();
    {
        float acc[12];
        #pragma unroll
        for (int i = 0; i < 12; ++i) acc[i] = 0.0f;
        for (int jj = 0; jj < D; ++jj) {
            float u = U[jj * D + j];
            #pragma unroll
            for (int e = 0; e < 4; ++e)
                #pragma unroll
                for (int r = 0; r < 3; ++r)
                    acc[e * 3 + r] += xj[grp * 4 + e][r * D + jj] * u;
        }
        #pragma unroll
        for (int e = 0; e < 4; ++e)
            #pragma unroll
            for (int r = 0; r < 3; ++r)
                vu[grp * 4 + e][r * D + j] = acc[e * 3 + r];
    }
    __syncthreads();
    {
        float acc[12];
        #pragma unroll
        for (int i = 0; i < 12; ++i) acc[i] = 0.0f;
        for (int jj = 0; jj < D; ++jj) {
            float v = V[jj * D + j];
            #pragma unroll
            for (int e = 0; e < 4; ++e)
                #pragma unroll
                for (int r = 0; r < 3; ++r)
                    acc[e * 3 + r] += vu[grp * 4 + e][r * D + jj] * v;
        }
        #pragma unroll
        for (int e = 0; e < 4; ++e)
            #pragma unroll
            for (int r = 0; r < 3; ++r)
                vv[grp * 4 + e][r * D + j] = acc[e * 3 + r];
    }
    __syncthreads();
    #pragma unroll
    for (int e = 0; e < 4; ++e) {
        int ee = grp * 4 + e;
        float a = vv[ee][3 * j], b = vv[ee][3 * j + 1], c = vv[ee][3 * j + 2];
        nrm[ee][j] = sqrtf(a * a + b * b + c * c);
    }
    __syncthreads();
    {
        float acc[4];
        float bk = bu1[j];
        #pragma unroll
        for (int e = 0; e < 4; ++e) acc[e] = bk;
        for (int jj = 0; jj < D; ++jj) {
            float wa = Wu1[jj * D + j];
            #pragma unroll
            for (int e = 0; e < 4; ++e) acc[e] += nrm[grp * 4 + e][jj] * wa;
        }
        for (int jj = 0; jj < D; ++jj) {
            float wb = Wu1[(D + jj) * D + j];
            #pragma unroll
            for (int e = 0; e < 4; ++e) acc[e] += xj[grp * 4 + e][384 + jj] * wb;
        }
        #pragma unroll
        for (int e = 0; e < 4; ++e) h1[grp * 4 + e][j] = silu_f(acc[e]);
    }
    __syncthreads();
    {
        float a1[4], a3[4];
        float bs1 = bu2[j], bs3 = bu2[256 + j];
        #pragma unroll
        for (int e = 0; e < 4; ++e) { a1[e] = bs1; a3[e] = bs3; }
        for (int jj = 0; jj < D; ++jj) {
            float w1 = Wu2[jj * 384 + j];
            float w3 = Wu2[jj * 384 + 256 + j];
            #pragma unroll
            for (int e = 0; e < 4; ++e) {
                float h = h1[grp * 4 + e][jj];
                a1[e] += h * w1;
                a3[e] += h * w3;
            }
        }
        #pragma unroll
        for (int e = 0; e < 4; ++e) {
            int ee = grp * 4 + e;
            int dst = dstl[ee];
            float* xd = xacc2 + (size_t)dst * FEAT;
            float dot = 0.0f;
            #pragma unroll
            for (int c = 0; c < 3; ++c) {
                float vf = vu[ee][3 * j + c] * a1[e];
                dot += vf * vv[ee][3 * j + c];
                atomicAdd(xd + 3 * j + c, vf);
            }
            atomicAdd(xd + 384 + j, dot + a3[e]);
        }
    }
}

__global__ __launch_bounds__(256) void k_final(float4* __restrict__ out,
                                               const float4* __restrict__ xacc2) {
    int i = blockIdx.x * blockDim.x + threadIdx.x;
    if (i < N_NODES * FEAT / 4) {
        float4 a = out[i], b = xacc2[i];
        out[i] = make_float4(a.x + b.x, a.y + b.y, a.z + b.z, a.w + b.w);
    }
}

// =================================================================== launch
extern "C" void kernel_launch(void* const* d_in, const int* in_sizes, int n_in,
                              void* d_out, int out_size, void* d_ws, size_t ws_size,
                              hipStream_t stream) {
    (void)in_sizes; (void)n_in; (void)out_size;
    const float* x   = (const float*)d_in[0];
    const int*   ei  = (const int*)d_in[1];
    const float* ea1 = (const float*)d_in[2];
    const float* ea2 = (const float*)d_in[3];
    const float* W1  = (const float*)d_in[4];
    const float* b1  = (const float*)d_in[5];
    const float* W2  = (const float*)d_in[6];
    const float* b2  = (const float*)d_in[7];
    const float* W3  = (const float*)d_in[8];
    const float* b3  = (const float*)d_in[9];
    const float* U   = (const float*)d_in[10];
    const float* V   = (const float*)d_in[11];
    const float* Wu1 = (const float*)d_in[12];
    const float* bu1 = (const float*)d_in[13];
    const float* Wu2 = (const float*)d_in[14];
    const float* bu2 = (const float*)d_in[15];
    float* out = (float*)d_out;

    // ws layout: msg(bf16 E*512) | offsets(N+1) | count(N) | cursor(N) | bucket(E)
    const size_t MSG_ELEMS = (size_t)N_EDGES * FEAT;
    const size_t NEED = MSG_ELEMS * 2 + sizeof(int) * (size_t)(N_NODES * 3 + 1 + N_EDGES) + 256;

    if (ws_size >= NEED) {
        __hip_bfloat16* msg = (__hip_bfloat16*)d_ws;
        int* offsets = (int*)((char*)d_ws + MSG_ELEMS * 2);
        int* count   = offsets + (N_NODES + 1);
        int* cursor  = count + N_NODES;
        int* bucket  = cursor + N_NODES;

        k_zero_ints<<<(2 * N_NODES + 255) / 256, 256, 0, stream>>>(count, 2 * N_NODES); // count+cursor contiguous
        k_count    <<<(N_EDGES + 255) / 256,     256, 0, stream>>>(ei, count);
        k_scan     <<<1,                         256, 0, stream>>>(count, offsets);
        k_bin      <<<(N_EDGES + 255) / 256,     256, 0, stream>>>(ei, offsets, cursor, bucket);

        k_p1msg    <<<N_EDGES / EPB1, 256, 0, stream>>>(x, ei, ea1, ea2, W1, b1, W2, b2, W3, b3, msg);
        k_gather   <<<N_NODES,        256, 0, stream>>>(msg, offsets, bucket, x, out);
        k_p2msg    <<<N_EDGES / EPB2, 256, 0, stream>>>(ei, U, V, Wu1, bu1, Wu2, bu2, out, msg);
        k_gather   <<<N_NODES,        256, 0, stream>>>(msg, offsets, bucket, out, out);
    } else {
        // fallback: round-2 atomic path (needs only 21 MB ws)
        float* xacc2 = (float*)d_ws;
        const int NV4 = N_NODES * FEAT / 4;
        k_init         <<<(NV4 + 255) / 256, 256, 0, stream>>>((const float4*)x, (float4*)out, (float4*)xacc2);
        k_phase1_atomic<<<N_EDGES / EPB1,    256, 0, stream>>>(x, ei, ea1, ea2, W1, b1, W2, b2, W3, b3, out);
        k_phase2_atomic<<<N_EDGES / EPB2,    256, 0, stream>>>(ei, U, V, Wu1, bu1, Wu2, bu2, out, xacc2);
        k_final        <<<(NV4 + 255) / 256, 256, 0, stream>>>((float4*)out, (const float4*)xacc2);
    }
}

// Round 4
// 441.270 us; speedup vs baseline: 7.2222x; 6.8090x over previous
//
#include <hip/hip_runtime.h>
#include <hip/hip_bf16.h>

#define N_NODES 10000
#define N_EDGES 160000
#define FEAT 512
#define D 128
#define NRBF 20
#define RCUT 1.4415f

__device__ __forceinline__ float silu_f(float x) { return x / (1.0f + __expf(-x)); }

// ================================================================= CSR build
__global__ __launch_bounds__(256) void k_zero_ints(int* __restrict__ p, int n) {
    int i = blockIdx.x * blockDim.x + threadIdx.x;
    if (i < n) p[i] = 0;
}

__global__ __launch_bounds__(256) void k_count(const int* __restrict__ ei,
                                               int* __restrict__ count) {
    int e = blockIdx.x * blockDim.x + threadIdx.x;
    if (e < N_EDGES) atomicAdd(&count[ei[N_EDGES + e]], 1);
}

// single block, 256 threads, chunk=40 -> exclusive prefix over 10000 nodes
__global__ __launch_bounds__(256) void k_scan(const int* __restrict__ count,
                                              int* __restrict__ offsets) {
    __shared__ int sums[256];
    const int t = threadIdx.x;
    const int base = t * 40;
    int s = 0;
    for (int i = 0; i < 40; ++i) {
        int idx = base + i;
        if (idx < N_NODES) s += count[idx];
    }
    sums[t] = s;
    __syncthreads();
    for (int off = 1; off < 256; off <<= 1) {
        int v = (t >= off) ? sums[t - off] : 0;
        __syncthreads();
        sums[t] += v;
        __syncthreads();
    }
    int run = (t == 0) ? 0 : sums[t - 1];
    for (int i = 0; i < 40; ++i) {
        int idx = base + i;
        if (idx < N_NODES) { offsets[idx] = run; run += count[idx]; }
    }
    if (t == 255) offsets[N_NODES] = run;
}

__global__ __launch_bounds__(256) void k_bin(const int* __restrict__ ei,
                                             const int* __restrict__ offsets,
                                             int* __restrict__ cursor,
                                             int* __restrict__ bke,
                                             int* __restrict__ bks) {
    int e = blockIdx.x * blockDim.x + threadIdx.x;
    if (e < N_EDGES) {
        int d = ei[N_EDGES + e];
        int pos = offsets[d] + atomicAdd(&cursor[d], 1);
        bke[pos] = e;
        bks[pos] = ei[e];   // src
    }
}

// ================================================================ k_basis
// basis[e][n] = sqrt(2/RCUT)*sin((n+1)*pi*r/RCUT)/r * 0.5*(cos(pi*r/RCUT)+1)*(r<RCUT)
__global__ __launch_bounds__(256) void k_basis(const float* __restrict__ ea2,
                                               float* __restrict__ basis) {
    int i = blockIdx.x * blockDim.x + threadIdx.x;
    if (i < N_EDGES * NRBF) {
        int e = i / NRBF, n = i % NRBF;
        float r  = ea2[e];
        float pr = 3.14159265358979f * r / RCUT;
        float rbf = sqrtf(2.0f / RCUT) * __sinf((float)(n + 1) * pr) / r;
        float cut = 0.5f * (__cosf(pr) + 1.0f) * (r < RCUT ? 1.0f : 0.0f);
        basis[i] = rbf * cut;
    }
}

// ================================================================ k_A
// A[n] = silu(x[n,384:] @ W1 + b1) @ W3 + b3      (N x 384, fp32)
#define NPB1 16
__global__ __launch_bounds__(256) void k_A(
    const float* __restrict__ x,
    const float* __restrict__ W1, const float* __restrict__ b1,
    const float* __restrict__ W3, const float* __restrict__ b3,
    float* __restrict__ A)
{
    __shared__ float sj[NPB1][D];
    __shared__ float tt[NPB1][D];
    const int t = threadIdx.x;
    const int j = t & 127;
    const int grp = t >> 7;          // 0/1, 8 nodes each
    const int n0 = blockIdx.x * NPB1;

    #pragma unroll
    for (int e = 0; e < 8; ++e) {
        int ee = grp * 8 + e;
        sj[ee][j] = x[(size_t)(n0 + ee) * FEAT + 384 + j];
    }
    __syncthreads();

    {
        float b1k = b1[j];
        float acc[8];
        #pragma unroll
        for (int e = 0; e < 8; ++e) acc[e] = b1k;
        for (int jj = 0; jj < D; ++jj) {
            float w = W1[jj * D + j];
            #pragma unroll
            for (int e = 0; e < 8; ++e) acc[e] += sj[grp * 8 + e][jj] * w;
        }
        #pragma unroll
        for (int e = 0; e < 8; ++e) tt[grp * 8 + e][j] = silu_f(acc[e]);
    }
    __syncthreads();

    #pragma unroll
    for (int c3 = 0; c3 < 3; ++c3) {
        const int k2 = c3 * D + j;
        float accf[8];
        float b3k = b3[k2];
        #pragma unroll
        for (int e = 0; e < 8; ++e) accf[e] = b3k;
        for (int jj = 0; jj < D; ++jj) {
            float w = W3[jj * 384 + k2];
            #pragma unroll
            for (int e = 0; e < 8; ++e) accf[e] += tt[grp * 8 + e][jj] * w;
        }
        #pragma unroll
        for (int e = 0; e < 8; ++e) A[(size_t)(n0 + grp * 8 + e) * 384 + k2] = accf[e];
    }
}

// ================================================================ k_gather1
// For dst d: out[d] = x[d] + sum_{e in CSR[d]} msg(e), msg computed on the fly.
// thread j (0..127): v cols (3j..3j+2) and scal col 384+j.
#define CH 8
__global__ __launch_bounds__(128) void k_gather1(
    const float* __restrict__ x,
    const float* __restrict__ A,
    const float* __restrict__ basis,
    const float* __restrict__ ea1,
    const float* __restrict__ W2, const float* __restrict__ b2,
    const int* __restrict__ offsets,
    const int* __restrict__ bke, const int* __restrict__ bks,
    float* __restrict__ out)
{
    __shared__ float w2l[NRBF][384];   // 30 KB
    __shared__ float ebl[CH][NRBF];
    __shared__ float eall[CH][3];
    __shared__ int srcl[CH], ekl[CH];

    const int d = blockIdx.x, t = threadIdx.x;  // t < 128
    for (int i = t; i < NRBF * 384; i += 128) w2l[i / 384][i % 384] = W2[i];

    const float b2a = b2[t], b2b = b2[128 + t], b2c = b2[256 + t];
    float acc0 = 0.f, acc1 = 0.f, acc2 = 0.f, accs = 0.f;
    const int o0 = offsets[d], o1 = offsets[d + 1];

    for (int bi = o0; bi < o1; bi += CH) {
        const int nch = min(CH, o1 - bi);
        __syncthreads();
        if (t < nch) { srcl[t] = bks[bi + t]; ekl[t] = bke[bi + t]; }
        __syncthreads();
        for (int i = t; i < nch * NRBF; i += 128)
            ebl[i / NRBF][i % NRBF] = basis[(size_t)ekl[i / NRBF] * NRBF + (i % NRBF)];
        for (int i = t; i < nch * 3; i += 128)
            eall[i / 3][i % 3] = ea1[(size_t)ekl[i / 3] * 3 + (i % 3)];
        __syncthreads();

        for (int ee = 0; ee < nch; ++ee) {
            const int s = srcl[ee];
            const float* Ar = A + (size_t)s * 384;
            const float* xr = x + (size_t)s * FEAT;
            float ebA = b2a, ebB = b2b, ebC = b2c;
            #pragma unroll
            for (int n = 0; n < NRBF; ++n) {
                float e = ebl[ee][n];
                ebA += e * w2l[n][t];
                ebB += e * w2l[n][128 + t];
                ebC += e * w2l[n][256 + t];
            }
            float s1 = Ar[t] * ebA;
            float s2 = Ar[128 + t] * ebB;
            float s3 = Ar[256 + t] * ebC;
            acc0 += xr[3 * t]     * s1 + s3 * eall[ee][0];
            acc1 += xr[3 * t + 1] * s1 + s3 * eall[ee][1];
            acc2 += xr[3 * t + 2] * s1 + s3 * eall[ee][2];
            accs += s2;
        }
    }

    const size_t ro = (size_t)d * FEAT;
    out[ro + 3 * t]     = x[ro + 3 * t]     + acc0;
    out[ro + 3 * t + 1] = x[ro + 3 * t + 1] + acc1;
    out[ro + 3 * t + 2] = x[ro + 3 * t + 2] + acc2;
    out[ro + 384 + t]   = x[ro + 384 + t]   + accs;
}

// ================================================================ k_B
// Per-node phase-2 message M2[n] (bf16, perm layout: [c*128+j]=v[j][c], [384+j]=scal)
#define NPB2 8
__global__ __launch_bounds__(256) void k_B(
    const float* __restrict__ U,
    const float* __restrict__ V,
    const float* __restrict__ Wu1, const float* __restrict__ bu1,
    const float* __restrict__ Wu2, const float* __restrict__ bu2,
    const float* __restrict__ xin,
    __hip_bfloat16* __restrict__ M2)
{
    __shared__ float xj[NPB2][FEAT];
    __shared__ float vu[NPB2][384];
    __shared__ float vv[NPB2][384];
    __shared__ float nrm[NPB2][D];
    __shared__ float h1[NPB2][D];

    const int t = threadIdx.x;
    const int j = t & 127;
    const int grp = t >> 7;
    const int n0 = blockIdx.x * NPB2;

    for (int i = t; i < NPB2 * FEAT; i += 256) {
        int e = i >> 9, f = i & 511;
        xj[e][f] = xin[(size_t)(n0 + e) * FEAT + f];
    }
    __syncthreads();

    // vu = (3,128) view of xj[:384] @ U
    {
        float acc[12];
        #pragma unroll
        for (int i = 0; i < 12; ++i) acc[i] = 0.0f;
        for (int jj = 0; jj < D; ++jj) {
            float u = U[jj * D + j];
            #pragma unroll
            for (int e = 0; e < 4; ++e)
                #pragma unroll
                for (int r = 0; r < 3; ++r)
                    acc[e * 3 + r] += xj[grp * 4 + e][r * D + jj] * u;
        }
        #pragma unroll
        for (int e = 0; e < 4; ++e)
            #pragma unroll
            for (int r = 0; r < 3; ++r)
                vu[grp * 4 + e][r * D + j] = acc[e * 3 + r];
    }
    __syncthreads();

    // vv = vu @ V
    {
        float acc[12];
        #pragma unroll
        for (int i = 0; i < 12; ++i) acc[i] = 0.0f;
        for (int jj = 0; jj < D; ++jj) {
            float v = V[jj * D + j];
            #pragma unroll
            for (int e = 0; e < 4; ++e)
                #pragma unroll
                for (int r = 0; r < 3; ++r)
                    acc[e * 3 + r] += vu[grp * 4 + e][r * D + jj] * v;
        }
        #pragma unroll
        for (int e = 0; e < 4; ++e)
            #pragma unroll
            for (int r = 0; r < 3; ++r)
                vv[grp * 4 + e][r * D + j] = acc[e * 3 + r];
    }
    __syncthreads();

    #pragma unroll
    for (int e = 0; e < 4; ++e) {
        int ee = grp * 4 + e;
        float a = vv[ee][3 * j], b = vv[ee][3 * j + 1], c = vv[ee][3 * j + 2];
        nrm[ee][j] = sqrtf(a * a + b * b + c * c);
    }
    __syncthreads();

    // h1 = silu([norm, s] @ Wu1 + bu1)
    {
        float acc[4];
        float bk = bu1[j];
        #pragma unroll
        for (int e = 0; e < 4; ++e) acc[e] = bk;
        for (int jj = 0; jj < D; ++jj) {
            float wa = Wu1[jj * D + j];
            #pragma unroll
            for (int e = 0; e < 4; ++e) acc[e] += nrm[grp * 4 + e][jj] * wa;
        }
        for (int jj = 0; jj < D; ++jj) {
            float wb = Wu1[(D + jj) * D + j];
            #pragma unroll
            for (int e = 0; e < 4; ++e) acc[e] += xj[grp * 4 + e][384 + jj] * wb;
        }
        #pragma unroll
        for (int e = 0; e < 4; ++e) h1[grp * 4 + e][j] = silu_f(acc[e]);
    }
    __syncthreads();

    // h = h1 @ Wu2 + bu2 (cols s1, s3); emit M2
    {
        float a1[4], a3[4];
        float bs1 = bu2[j], bs3 = bu2[256 + j];
        #pragma unroll
        for (int e = 0; e < 4; ++e) { a1[e] = bs1; a3[e] = bs3; }
        for (int jj = 0; jj < D; ++jj) {
            float w1 = Wu2[jj * 384 + j];
            float w3 = Wu2[jj * 384 + 256 + j];
            #pragma unroll
            for (int e = 0; e < 4; ++e) {
                float h = h1[grp * 4 + e][jj];
                a1[e] += h * w1;
                a3[e] += h * w3;
            }
        }
        #pragma unroll
        for (int e = 0; e < 4; ++e) {
            int ee = grp * 4 + e;
            __hip_bfloat16* mrow = M2 + (size_t)(n0 + ee) * FEAT;
            float dot = 0.0f;
            #pragma unroll
            for (int c = 0; c < 3; ++c) {
                float vf = vu[ee][3 * j + c] * a1[e];
                dot += vf * vv[ee][3 * j + c];
                mrow[c * 128 + j] = __float2bfloat16(vf);
            }
            mrow[384 + j] = __float2bfloat16(dot + a3[e]);
        }
    }
}

// ================================================================ k_gather2
// out[d][g] = out[d][g] + sum_{e in CSR[d]} M2[src(e)][perm(g)]
__global__ __launch_bounds__(256) void k_gather2(
    const __hip_bfloat16* __restrict__ M2,
    const int* __restrict__ offsets,
    const int* __restrict__ bks,
    float* __restrict__ out)
{
    __shared__ float row[FEAT];
    const int d = blockIdx.x, t = threadIdx.x;
    const int o0 = offsets[d], o1 = offsets[d + 1];
    float a0 = 0.0f, a1 = 0.0f;
    for (int i = o0; i < o1; ++i) {
        int s = bks[i];
        const __hip_bfloat162* r = (const __hip_bfloat162*)(M2 + (size_t)s * FEAT);
        __hip_bfloat162 v = r[t];
        a0 += __bfloat162float(v.x);
        a1 += __bfloat162float(v.y);
    }
    row[2 * t]     = a0;
    row[2 * t + 1] = a1;
    __syncthreads();
    #pragma unroll
    for (int gi = 0; gi < 2; ++gi) {
        int g = t + gi * 256;
        int m = (g < 384) ? ((g % 3) * 128 + g / 3) : g;
        out[(size_t)d * FEAT + g] += row[m];
    }
}

// ====================== fallback path (atomic version, ws >= 21 MB) =========
__global__ __launch_bounds__(256) void k_init(const float4* __restrict__ x,
                                              float4* __restrict__ xacc,
                                              float4* __restrict__ xacc2) {
    int i = blockIdx.x * blockDim.x + threadIdx.x;
    if (i < N_NODES * FEAT / 4) {
        xacc[i]  = x[i];
        xacc2[i] = make_float4(0.f, 0.f, 0.f, 0.f);
    }
}

#define EPB1 16
__global__ __launch_bounds__(256) void k_phase1_atomic(
    const float* __restrict__ x, const int* __restrict__ ei,
    const float* __restrict__ ea1, const float* __restrict__ ea2,
    const float* __restrict__ W1, const float* __restrict__ b1,
    const float* __restrict__ W2, const float* __restrict__ b2,
    const float* __restrict__ W3, const float* __restrict__ b3,
    float* __restrict__ xacc)
{
    __shared__ float sj[EPB1][D];
    __shared__ float tt[EPB1][D];
    __shared__ float basis[EPB1][NRBF];
    __shared__ float eal[EPB1][3];
    __shared__ int srcl[EPB1], dstl[EPB1];
    const int t = threadIdx.x;
    const int j = t & 127;
    const int grp = t >> 7;
    const int e0 = blockIdx.x * EPB1;
    if (t < EPB1) { srcl[t] = ei[e0 + t]; dstl[t] = ei[N_EDGES + e0 + t]; }
    if (t >= 64 && t < 64 + EPB1 * 3) {
        int i2 = t - 64;
        eal[i2 / 3][i2 % 3] = ea1[(e0 + i2 / 3) * 3 + (i2 % 3)];
    }
    __syncthreads();
    #pragma unroll
    for (int e = 0; e < 8; ++e) {
        int ee = grp * 8 + e;
        sj[ee][j] = x[(size_t)srcl[ee] * FEAT + 384 + j];
    }
    for (int i = t; i < EPB1 * NRBF; i += 256) {
        int e = i / NRBF, n = i % NRBF;
        float r  = ea2[e0 + e];
        float pr = 3.14159265358979f * r / RCUT;
        float rbf = sqrtf(2.0f / RCUT) * sinf((float)(n + 1) * pr) / r;
        float cut = 0.5f * (cosf(pr) + 1.0f) * (r < RCUT ? 1.0f : 0.0f);
        basis[e][n] = rbf * cut;
    }
    __syncthreads();
    {
        float b1k = b1[j];
        float acc[8];
        #pragma unroll
        for (int e = 0; e < 8; ++e) acc[e] = b1k;
        for (int jj = 0; jj < D; ++jj) {
            float w = W1[jj * D + j];
            #pragma unroll
            for (int e = 0; e < 8; ++e) acc[e] += sj[grp * 8 + e][jj] * w;
        }
        #pragma unroll
        for (int e = 0; e < 8; ++e) tt[grp * 8 + e][j] = silu_f(acc[e]);
    }
    __syncthreads();
    float sp[3][8];
    #pragma unroll
    for (int c3 = 0; c3 < 3; ++c3) {
        const int k2 = c3 * D + j;
        float accf[8], accb[8];
        float b3k = b3[k2];
        float b2k = b2[k2];
        #pragma unroll
        for (int e = 0; e < 8; ++e) { accf[e] = b3k; accb[e] = b2k; }
        for (int jj = 0; jj < D; ++jj) {
            float w = W3[jj * 384 + k2];
            #pragma unroll
            for (int e = 0; e < 8; ++e) accf[e] += tt[grp * 8 + e][jj] * w;
        }
        for (int n = 0; n < NRBF; ++n) {
            float w = W2[n * 384 + k2];
            #pragma unroll
            for (int e = 0; e < 8; ++e) accb[e] += basis[grp * 8 + e][n] * w;
        }
        #pragma unroll
        for (int e = 0; e < 8; ++e) sp[c3][e] = accf[e] * accb[e];
    }
    #pragma unroll
    for (int e = 0; e < 8; ++e) {
        int ee = grp * 8 + e;
        int src = srcl[ee], dst = dstl[ee];
        float s1v = sp[0][e], s2v = sp[1][e], s3v = sp[2][e];
        float* xd = xacc + (size_t)dst * FEAT;
        #pragma unroll
        for (int c = 0; c < 3; ++c) {
            float vj = x[(size_t)src * FEAT + j * 3 + c];
            atomicAdd(xd + j * 3 + c, vj * s1v + s3v * eal[ee][c]);
        }
        atomicAdd(xd + 384 + j, s2v);
    }
}

#define EPB2 8
__global__ __launch_bounds__(256) void k_phase2_atomic(
    const int* __restrict__ ei,
    const float* __restrict__ U, const float* __restrict__ V,
    const float* __restrict__ Wu1, const float* __restrict__ bu1,
    const float* __restrict__ Wu2, const float* __restrict__ bu2,
    const float* __restrict__ xacc, float* __restrict__ xacc2)
{
    __shared__ float xj[EPB2][FEAT];
    __shared__ float vu[EPB2][384];
    __shared__ float vv[EPB2][384];
    __shared__ float nrm[EPB2][D];
    __shared__ float h1[EPB2][D];
    __shared__ int srcl[EPB2], dstl[EPB2];
    const int t = threadIdx.x;
    const int j = t & 127;
    const int grp = t >> 7;
    const int e0 = blockIdx.x * EPB2;
    if (t < EPB2) { srcl[t] = ei[e0 + t]; dstl[t] = ei[N_EDGES + e0 + t]; }
    __syncthreads();
    for (int i = t; i < EPB2 * FEAT; i += 256) {
        int e = i >> 9, f = i & 511;
        xj[e][f] = xacc[(size_t)srcl[e] * FEAT + f];
    }
    __syncthreads();
    {
        float acc[12];
        #pragma unroll
        for (int i = 0; i < 12; ++i) acc[i] = 0.0f;
        for (int jj = 0; jj < D; ++jj) {
            float u = U[jj * D + j];
            #pragma unroll
            for (int e = 0; e < 4; ++e)
                #pragma unroll
                for (int r = 0; r < 3; ++r)
                    acc[e * 3 + r] += xj[grp * 4 + e][r * D + jj] * u;
        }
        #pragma unroll
        for (int e = 0; e < 4; ++e)
            #pragma unroll
            for (int r = 0; r < 3; ++r)
                vu[grp * 4 + e][r * D + j] = acc[e * 3 + r];
    }
    __syncthreads();
    {
        float acc[12];
        #pragma unroll
        for (int i = 0; i < 12; ++i) acc[i] = 0.0f;
        for (int jj = 0; jj < D; ++jj) {
            float v = V[jj * D + j];
            #pragma unroll
            for (int e = 0; e < 4; ++e)
                #pragma unroll
                for (int r = 0; r < 3; ++r)
                    acc[e * 3 + r] += vu[grp * 4 + e][r * D + jj] * v;
        }
        #pragma unroll
        for (int e = 0; e < 4; ++e)
            #pragma unroll
            for (int r = 0; r < 3; ++r)
                vv[grp * 4 + e][r * D + j] = acc[e * 3 + r];
    }
    __syncthreads();
    #pragma unroll
    for (int e = 0; e < 4; ++e) {
        int ee = grp * 4 + e;
        float a = vv[ee][3 * j], b = vv[ee][3 * j + 1], c = vv[ee][3 * j + 2];
        nrm[ee][j] = sqrtf(a * a + b * b + c * c);
    }
    __syncthreads();
    {
        float acc[4];
        float bk = bu1[j];
        #pragma unroll
        for (int e = 0; e < 4; ++e) acc[e] = bk;
        for (int jj = 0; jj < D; ++jj) {
            float wa = Wu1[jj * D + j];
            #pragma unroll
            for (int e = 0; e < 4; ++e) acc[e] += nrm[grp * 4 + e][jj] * wa;
        }
        for (int jj = 0; jj < D; ++jj) {
            float wb = Wu1[(D + jj) * D + j];
            #pragma unroll
            for (int e = 0; e < 4; ++e) acc[e] += xj[grp * 4 + e][384 + jj] * wb;
        }
        #pragma unroll
        for (int e = 0; e < 4; ++e) h1[grp * 4 + e][j] = silu_f(acc[e]);
    }
    __syncthreads();
    {
        float a1[4], a3[4];
        float bs1 = bu2[j], bs3 = bu2[256 + j];
        #pragma unroll
        for (int e = 0; e < 4; ++e) { a1[e] = bs1; a3[e] = bs3; }
        for (int jj = 0; jj < D; ++jj) {
            float w1 = Wu2[jj * 384 + j];
            float w3 = Wu2[jj * 384 + 256 + j];
            #pragma unroll
            for (int e = 0; e < 4; ++e) {
                float h = h1[grp * 4 + e][jj];
                a1[e] += h * w1;
                a3[e] += h * w3;
            }
        }
        #pragma unroll
        for (int e = 0; e < 4; ++e) {
            int ee = grp * 4 + e;
            int dst = dstl[ee];
            float* xd = xacc2 + (size_t)dst * FEAT;
            float dot = 0.0f;
            #pragma unroll
            for (int c = 0; c < 3; ++c) {
                float vf = vu[ee][3 * j + c] * a1[e];
                dot += vf * vv[ee][3 * j + c];
                atomicAdd(xd + 3 * j + c, vf);
            }
            atomicAdd(xd + 384 + j, dot + a3[e]);
        }
    }
}

__global__ __launch_bounds__(256) void k_final(float4* __restrict__ out,
                                               const float4* __restrict__ xacc2) {
    int i = blockIdx.x * blockDim.x + threadIdx.x;
    if (i < N_NODES * FEAT / 4) {
        float4 a = out[i], b = xacc2[i];
        out[i] = make_float4(a.x + b.x, a.y + b.y, a.z + b.z, a.w + b.w);
    }
}

// =================================================================== launch
extern "C" void kernel_launch(void* const* d_in, const int* in_sizes, int n_in,
                              void* d_out, int out_size, void* d_ws, size_t ws_size,
                              hipStream_t stream) {
    (void)in_sizes; (void)n_in; (void)out_size;
    const float* x   = (const float*)d_in[0];
    const int*   ei  = (const int*)d_in[1];
    const float* ea1 = (const float*)d_in[2];
    const float* ea2 = (const float*)d_in[3];
    const float* W1  = (const float*)d_in[4];
    const float* b1  = (const float*)d_in[5];
    const float* W2  = (const float*)d_in[6];
    const float* b2  = (const float*)d_in[7];
    const float* W3  = (const float*)d_in[8];
    const float* b3  = (const float*)d_in[9];
    const float* U   = (const float*)d_in[10];
    const float* V   = (const float*)d_in[11];
    const float* Wu1 = (const float*)d_in[12];
    const float* bu1 = (const float*)d_in[13];
    const float* Wu2 = (const float*)d_in[14];
    const float* bu2 = (const float*)d_in[15];
    float* out = (float*)d_out;

    // ws layout: A f32 N*384 | basis f32 E*20 | M2 bf16 N*512 | ints
    const size_t A_BYTES     = (size_t)N_NODES * 384 * 4;
    const size_t BASIS_BYTES = (size_t)N_EDGES * NRBF * 4;
    const size_t M2_BYTES    = (size_t)N_NODES * FEAT * 2;
    const size_t INT_COUNT   = (size_t)(N_NODES + 1) + 2 * N_NODES + 2 * N_EDGES;
    const size_t NEED = A_BYTES + BASIS_BYTES + M2_BYTES + INT_COUNT * 4 + 256;

    if (ws_size >= NEED) {
        float* A     = (float*)d_ws;
        float* basis = (float*)((char*)d_ws + A_BYTES);
        __hip_bfloat16* M2 = (__hip_bfloat16*)((char*)d_ws + A_BYTES + BASIS_BYTES);
        int* offsets = (int*)((char*)d_ws + A_BYTES + BASIS_BYTES + M2_BYTES);
        int* count   = offsets + (N_NODES + 1);
        int* cursor  = count + N_NODES;
        int* bke     = cursor + N_NODES;
        int* bks     = bke + N_EDGES;

        k_zero_ints<<<(2 * N_NODES + 255) / 256,     256, 0, stream>>>(count, 2 * N_NODES);
        k_count    <<<(N_EDGES + 255) / 256,         256, 0, stream>>>(ei, count);
        k_scan     <<<1,                             256, 0, stream>>>(count, offsets);
        k_bin      <<<(N_EDGES + 255) / 256,         256, 0, stream>>>(ei, offsets, cursor, bke, bks);
        k_basis    <<<(N_EDGES * NRBF + 255) / 256,  256, 0, stream>>>(ea2, basis);

        k_A        <<<N_NODES / NPB1, 256, 0, stream>>>(x, W1, b1, W3, b3, A);
        k_gather1  <<<N_NODES,        128, 0, stream>>>(x, A, basis, ea1, W2, b2, offsets, bke, bks, out);
        k_B        <<<N_NODES / NPB2, 256, 0, stream>>>(U, V, Wu1, bu1, Wu2, bu2, out, M2);
        k_gather2  <<<N_NODES,        256, 0, stream>>>(M2, offsets, bks, out);
    } else {
        // fallback: atomic path (needs only ~21 MB ws)
        float* xacc2 = (float*)d_ws;
        const int NV4 = N_NODES * FEAT / 4;
        k_init         <<<(NV4 + 255) / 256, 256, 0, stream>>>((const float4*)x, (float4*)out, (float4*)xacc2);
        k_phase1_atomic<<<N_EDGES / EPB1,    256, 0, stream>>>(x, ei, ea1, ea2, W1, b1, W2, b2, W3, b3, out);
        k_phase2_atomic<<<N_EDGES / EPB2,    256, 0, stream>>>(ei, U, V, Wu1, bu1, Wu2, bu2, out, xacc2);
        k_final        <<<(NV4 + 255) / 256, 256, 0, stream>>>((float4*)out, (const float4*)xacc2);
    }
}

// Round 5
// 423.495 us; speedup vs baseline: 7.5254x; 1.0420x over previous
//
#include <hip/hip_runtime.h>
#include <hip/hip_bf16.h>

#define N_NODES 10000
#define N_EDGES 160000
#define FEAT 512
#define D 128
#define NRBF 20
#define RCUT 1.4415f

__device__ __forceinline__ float silu_f(float x) { return x / (1.0f + __expf(-x)); }

// ================================================================= CSR build
__global__ __launch_bounds__(256) void k_zero_ints(int* __restrict__ p, int n) {
    int i = blockIdx.x * blockDim.x + threadIdx.x;
    if (i < n) p[i] = 0;
}

__global__ __launch_bounds__(256) void k_count(const int* __restrict__ ei,
                                               int* __restrict__ count) {
    int e = blockIdx.x * blockDim.x + threadIdx.x;
    if (e < N_EDGES) atomicAdd(&count[ei[N_EDGES + e]], 1);
}

__global__ __launch_bounds__(256) void k_scan(const int* __restrict__ count,
                                              int* __restrict__ offsets) {
    __shared__ int sums[256];
    const int t = threadIdx.x;
    const int base = t * 40;
    int s = 0;
    for (int i = 0; i < 40; ++i) {
        int idx = base + i;
        if (idx < N_NODES) s += count[idx];
    }
    sums[t] = s;
    __syncthreads();
    for (int off = 1; off < 256; off <<= 1) {
        int v = (t >= off) ? sums[t - off] : 0;
        __syncthreads();
        sums[t] += v;
        __syncthreads();
    }
    int run = (t == 0) ? 0 : sums[t - 1];
    for (int i = 0; i < 40; ++i) {
        int idx = base + i;
        if (idx < N_NODES) { offsets[idx] = run; run += count[idx]; }
    }
    if (t == 255) offsets[N_NODES] = run;
}

__global__ __launch_bounds__(256) void k_bin(const int* __restrict__ ei,
                                             const int* __restrict__ offsets,
                                             int* __restrict__ cursor,
                                             int* __restrict__ bke,
                                             int* __restrict__ bks) {
    int e = blockIdx.x * blockDim.x + threadIdx.x;
    if (e < N_EDGES) {
        int d = ei[N_EDGES + e];
        int pos = offsets[d] + atomicAdd(&cursor[d], 1);
        bke[pos] = e;
        bks[pos] = ei[e];
    }
}

// ================================================================ k_basis
__global__ __launch_bounds__(256) void k_basis(const float* __restrict__ ea2,
                                               float* __restrict__ basis) {
    int i = blockIdx.x * blockDim.x + threadIdx.x;
    if (i < N_EDGES * NRBF) {
        int e = i / NRBF, n = i % NRBF;
        float r  = ea2[e];
        float pr = 3.14159265358979f * r / RCUT;
        float rbf = sqrtf(2.0f / RCUT) * __sinf((float)(n + 1) * pr) / r;
        float cut = 0.5f * (__cosf(pr) + 1.0f) * (r < RCUT ? 1.0f : 0.0f);
        basis[i] = rbf * cut;
    }
}

// ================================================================ k_A
// Ab[n][c*128+j] = (silu(x[n,384:]@W1+b1)@W3+b3)[c*128+j]  (bf16)
// xvp[n][c*128+j] = x[n][3j+c]  (bf16, permuted v-part)
#define NPB1 16
__global__ __launch_bounds__(256) void k_A(
    const float* __restrict__ x,
    const float* __restrict__ W1, const float* __restrict__ b1,
    const float* __restrict__ W3, const float* __restrict__ b3,
    __hip_bfloat16* __restrict__ Ab, __hip_bfloat16* __restrict__ xvp)
{
    __shared__ __align__(16) float sj[NPB1][D];
    __shared__ __align__(16) float tt[NPB1][D];
    const int t = threadIdx.x;
    const int j = t & 127;
    const int grp = t >> 7;
    const int n0 = blockIdx.x * NPB1;

    #pragma unroll
    for (int e = 0; e < 8; ++e) {
        int ee = grp * 8 + e;
        sj[ee][j] = x[(size_t)(n0 + ee) * FEAT + 384 + j];
    }
    // pack xvp (independent of sj)
    #pragma unroll
    for (int e = 0; e < 8; ++e) {
        int n = n0 + grp * 8 + e;
        #pragma unroll
        for (int c = 0; c < 3; ++c)
            xvp[(size_t)n * 384 + c * 128 + j] = __float2bfloat16(x[(size_t)n * FEAT + 3 * j + c]);
    }
    __syncthreads();

    {
        float b1k = b1[j];
        float acc[8];
        #pragma unroll
        for (int e = 0; e < 8; ++e) acc[e] = b1k;
        for (int jj = 0; jj < D; jj += 4) {
            float w0 = W1[(jj)     * D + j];
            float w1 = W1[(jj + 1) * D + j];
            float w2 = W1[(jj + 2) * D + j];
            float w3 = W1[(jj + 3) * D + j];
            #pragma unroll
            for (int e = 0; e < 8; ++e) {
                float4 s4 = *(const float4*)&sj[grp * 8 + e][jj];
                acc[e] += s4.x * w0 + s4.y * w1 + s4.z * w2 + s4.w * w3;
            }
        }
        #pragma unroll
        for (int e = 0; e < 8; ++e) tt[grp * 8 + e][j] = silu_f(acc[e]);
    }
    __syncthreads();

    #pragma unroll
    for (int c3 = 0; c3 < 3; ++c3) {
        const int k2 = c3 * D + j;
        float accf[8];
        float b3k = b3[k2];
        #pragma unroll
        for (int e = 0; e < 8; ++e) accf[e] = b3k;
        for (int jj = 0; jj < D; jj += 4) {
            float w0 = W3[(jj)     * 384 + k2];
            float w1 = W3[(jj + 1) * 384 + k2];
            float w2 = W3[(jj + 2) * 384 + k2];
            float w3 = W3[(jj + 3) * 384 + k2];
            #pragma unroll
            for (int e = 0; e < 8; ++e) {
                float4 s4 = *(const float4*)&tt[grp * 8 + e][jj];
                accf[e] += s4.x * w0 + s4.y * w1 + s4.z * w2 + s4.w * w3;
            }
        }
        #pragma unroll
        for (int e = 0; e < 8; ++e)
            Ab[(size_t)(n0 + grp * 8 + e) * 384 + k2] = __float2bfloat16(accf[e]);
    }
}

// ================================================================ k_gather1
// out[d] = x[d] + sum_{e in CSR[d]} msg(e); W2 in registers, bf16 A/xv reads.
#define CH 8
__global__ __launch_bounds__(128) void k_gather1(
    const float* __restrict__ x,
    const __hip_bfloat16* __restrict__ Ab,
    const __hip_bfloat16* __restrict__ xvp,
    const float* __restrict__ basis,
    const float* __restrict__ ea1,
    const float* __restrict__ W2, const float* __restrict__ b2,
    const int* __restrict__ offsets,
    const int* __restrict__ bke, const int* __restrict__ bks,
    float* __restrict__ out)
{
    __shared__ float ebl[CH][NRBF];
    __shared__ float eall[CH][3];
    __shared__ int srcl[CH], ekl[CH];

    const int d = blockIdx.x, t = threadIdx.x;   // 128 threads

    // W2 columns for this thread in registers (block-invariant)
    float w2r0[NRBF], w2r1[NRBF], w2r2[NRBF];
    #pragma unroll
    for (int n = 0; n < NRBF; ++n) {
        w2r0[n] = W2[n * 384 + t];
        w2r1[n] = W2[n * 384 + 128 + t];
        w2r2[n] = W2[n * 384 + 256 + t];
    }
    const float b2a = b2[t], b2b = b2[128 + t], b2c = b2[256 + t];

    float acc0 = 0.f, acc1 = 0.f, acc2 = 0.f, accs = 0.f;
    const int o0 = offsets[d], o1 = offsets[d + 1];

    for (int bi = o0; bi < o1; bi += CH) {
        __syncthreads();
        if (t < CH) {
            int idx = bi + t; if (idx >= o1) idx = o0;   // pad with a valid edge
            srcl[t] = bks[idx]; ekl[t] = bke[idx];
        }
        __syncthreads();
        for (int i = t; i < CH * NRBF; i += 128)
            ebl[i / NRBF][i % NRBF] = basis[(size_t)ekl[i / NRBF] * NRBF + (i % NRBF)];
        if (t < CH * 3) eall[t / 3][t % 3] = ea1[(size_t)ekl[t / 3] * 3 + (t % 3)];
        __syncthreads();

        // batch-load all CH edges' A and xv fragments (independent loads)
        float av[CH][3], xv[CH][3];
        #pragma unroll
        for (int ee = 0; ee < CH; ++ee) {
            const size_t s = (size_t)srcl[ee];
            const __hip_bfloat16* Ar = Ab + s * 384;
            const __hip_bfloat16* Xr = xvp + s * 384;
            av[ee][0] = __bfloat162float(Ar[t]);
            av[ee][1] = __bfloat162float(Ar[128 + t]);
            av[ee][2] = __bfloat162float(Ar[256 + t]);
            xv[ee][0] = __bfloat162float(Xr[t]);
            xv[ee][1] = __bfloat162float(Xr[128 + t]);
            xv[ee][2] = __bfloat162float(Xr[256 + t]);
        }

        #pragma unroll
        for (int ee = 0; ee < CH; ++ee) {
            float vm = (bi + ee < o1) ? 1.0f : 0.0f;
            float ebA = b2a, ebB = b2b, ebC = b2c;
            #pragma unroll
            for (int n = 0; n < NRBF; ++n) {
                float e = ebl[ee][n];
                ebA += e * w2r0[n];
                ebB += e * w2r1[n];
                ebC += e * w2r2[n];
            }
            float s1 = av[ee][0] * ebA;
            float s2 = av[ee][1] * ebB;
            float s3 = av[ee][2] * ebC;
            acc0 += vm * (xv[ee][0] * s1 + s3 * eall[ee][0]);
            acc1 += vm * (xv[ee][1] * s1 + s3 * eall[ee][1]);
            acc2 += vm * (xv[ee][2] * s1 + s3 * eall[ee][2]);
            accs += vm * s2;
        }
    }

    const size_t ro = (size_t)d * FEAT;
    out[ro + 3 * t]     = x[ro + 3 * t]     + acc0;
    out[ro + 3 * t + 1] = x[ro + 3 * t + 1] + acc1;
    out[ro + 3 * t + 2] = x[ro + 3 * t + 2] + acc2;
    out[ro + 384 + t]   = x[ro + 384 + t]   + accs;
}

// ================================================================ k_B
// Per-node phase-2 message M2[n] (bf16, perm layout: [c*128+j]=v[j][c], [384+j]=scal)
#define NPB2 8
__global__ __launch_bounds__(256) void k_B(
    const float* __restrict__ U,
    const float* __restrict__ V,
    const float* __restrict__ Wu1, const float* __restrict__ bu1,
    const float* __restrict__ Wu2, const float* __restrict__ bu2,
    const float* __restrict__ xin,
    __hip_bfloat16* __restrict__ M2)
{
    __shared__ __align__(16) float xs[NPB2][D];    // s-part         4 KB
    __shared__ __align__(16) float xv[NPB2][384];  // v-part, reused as vv  12 KB
    __shared__ __align__(16) float vu[NPB2][384];  // 12 KB
    __shared__ __align__(16) float nrm[NPB2][D];   // 4 KB
    __shared__ __align__(16) float h1[NPB2][D];    // 4 KB

    const int t = threadIdx.x;
    const int j = t & 127;
    const int grp = t >> 7;
    const int n0 = blockIdx.x * NPB2;

    for (int i = t; i < NPB2 * FEAT; i += 256) {
        int e = i >> 9, f = i & 511;
        float v = xin[(size_t)(n0 + e) * FEAT + f];
        if (f < 384) xv[e][f] = v; else xs[e][f - 384] = v;
    }
    __syncthreads();

    // vu = (3,128) view of xv @ U
    {
        float acc[12];
        #pragma unroll
        for (int i = 0; i < 12; ++i) acc[i] = 0.0f;
        for (int jj = 0; jj < D; jj += 4) {
            float w0 = U[(jj)     * D + j];
            float w1 = U[(jj + 1) * D + j];
            float w2 = U[(jj + 2) * D + j];
            float w3 = U[(jj + 3) * D + j];
            #pragma unroll
            for (int e = 0; e < 4; ++e)
                #pragma unroll
                for (int r = 0; r < 3; ++r) {
                    float4 s4 = *(const float4*)&xv[grp * 4 + e][r * D + jj];
                    acc[e * 3 + r] += s4.x * w0 + s4.y * w1 + s4.z * w2 + s4.w * w3;
                }
        }
        #pragma unroll
        for (int e = 0; e < 4; ++e)
            #pragma unroll
            for (int r = 0; r < 3; ++r)
                vu[grp * 4 + e][r * D + j] = acc[e * 3 + r];
    }
    __syncthreads();   // vu complete; all xv reads done

    // vv = vu @ V  -> stored into xv (reuse)
    {
        float acc[12];
        #pragma unroll
        for (int i = 0; i < 12; ++i) acc[i] = 0.0f;
        for (int jj = 0; jj < D; jj += 4) {
            float w0 = V[(jj)     * D + j];
            float w1 = V[(jj + 1) * D + j];
            float w2 = V[(jj + 2) * D + j];
            float w3 = V[(jj + 3) * D + j];
            #pragma unroll
            for (int e = 0; e < 4; ++e)
                #pragma unroll
                for (int r = 0; r < 3; ++r) {
                    float4 s4 = *(const float4*)&vu[grp * 4 + e][r * D + jj];
                    acc[e * 3 + r] += s4.x * w0 + s4.y * w1 + s4.z * w2 + s4.w * w3;
                }
        }
        #pragma unroll
        for (int e = 0; e < 4; ++e)
            #pragma unroll
            for (int r = 0; r < 3; ++r)
                xv[grp * 4 + e][r * D + j] = acc[e * 3 + r];   // xv now holds vv
    }
    __syncthreads();

    #pragma unroll
    for (int e = 0; e < 4; ++e) {
        int ee = grp * 4 + e;
        float a = xv[ee][3 * j], b = xv[ee][3 * j + 1], c = xv[ee][3 * j + 2];
        nrm[ee][j] = sqrtf(a * a + b * b + c * c);
    }
    __syncthreads();

    // h1 = silu([norm, s] @ Wu1 + bu1)
    {
        float acc[4];
        float bk = bu1[j];
        #pragma unroll
        for (int e = 0; e < 4; ++e) acc[e] = bk;
        for (int jj = 0; jj < D; jj += 4) {
            float wa0 = Wu1[(jj)     * D + j];
            float wa1 = Wu1[(jj + 1) * D + j];
            float wa2 = Wu1[(jj + 2) * D + j];
            float wa3 = Wu1[(jj + 3) * D + j];
            #pragma unroll
            for (int e = 0; e < 4; ++e) {
                float4 s4 = *(const float4*)&nrm[grp * 4 + e][jj];
                acc[e] += s4.x * wa0 + s4.y * wa1 + s4.z * wa2 + s4.w * wa3;
            }
        }
        for (int jj = 0; jj < D; jj += 4) {
            float wb0 = Wu1[(D + jj)     * D + j];
            float wb1 = Wu1[(D + jj + 1) * D + j];
            float wb2 = Wu1[(D + jj + 2) * D + j];
            float wb3 = Wu1[(D + jj + 3) * D + j];
            #pragma unroll
            for (int e = 0; e < 4; ++e) {
                float4 s4 = *(const float4*)&xs[grp * 4 + e][jj];
                acc[e] += s4.x * wb0 + s4.y * wb1 + s4.z * wb2 + s4.w * wb3;
            }
        }
        #pragma unroll
        for (int e = 0; e < 4; ++e) h1[grp * 4 + e][j] = silu_f(acc[e]);
    }
    __syncthreads();

    // h = h1 @ Wu2 + bu2 (cols s1, s3); emit M2
    {
        float a1[4], a3[4];
        float bs1 = bu2[j], bs3 = bu2[256 + j];
        #pragma unroll
        for (int e = 0; e < 4; ++e) { a1[e] = bs1; a3[e] = bs3; }
        for (int jj = 0; jj < D; jj += 4) {
            #pragma unroll
            for (int q = 0; q < 4; ++q) {
                float w1 = Wu2[(jj + q) * 384 + j];
                float w3 = Wu2[(jj + q) * 384 + 256 + j];
                #pragma unroll
                for (int e = 0; e < 4; ++e) {
                    float h = h1[grp * 4 + e][jj + q];
                    a1[e] += h * w1;
                    a3[e] += h * w3;
                }
            }
        }
        #pragma unroll
        for (int e = 0; e < 4; ++e) {
            int ee = grp * 4 + e;
            __hip_bfloat16* mrow = M2 + (size_t)(n0 + ee) * FEAT;
            float dot = 0.0f;
            #pragma unroll
            for (int c = 0; c < 3; ++c) {
                float vf = vu[ee][3 * j + c] * a1[e];
                dot += vf * xv[ee][3 * j + c];   // xv holds vv
                mrow[c * 128 + j] = __float2bfloat16(vf);
            }
            mrow[384 + j] = __float2bfloat16(dot + a3[e]);
        }
    }
}

// ================================================================ k_gather2
__global__ __launch_bounds__(256) void k_gather2(
    const __hip_bfloat16* __restrict__ M2,
    const int* __restrict__ offsets,
    const int* __restrict__ bks,
    float* __restrict__ out)
{
    __shared__ float row[FEAT];
    __shared__ int sl[32];
    const int d = blockIdx.x, t = threadIdx.x;
    const int o0 = offsets[d], o1 = offsets[d + 1];
    float a0 = 0.0f, a1 = 0.0f;
    for (int bi = o0; bi < o1; bi += 32) {
        int nch = min(32, o1 - bi);
        __syncthreads();
        if (t < nch) sl[t] = bks[bi + t];
        __syncthreads();
        int i = 0;
        for (; i + 4 <= nch; i += 4) {
            __hip_bfloat162 v0 = ((const __hip_bfloat162*)(M2 + (size_t)sl[i]     * FEAT))[t];
            __hip_bfloat162 v1 = ((const __hip_bfloat162*)(M2 + (size_t)sl[i + 1] * FEAT))[t];
            __hip_bfloat162 v2 = ((const __hip_bfloat162*)(M2 + (size_t)sl[i + 2] * FEAT))[t];
            __hip_bfloat162 v3 = ((const __hip_bfloat162*)(M2 + (size_t)sl[i + 3] * FEAT))[t];
            a0 += __bfloat162float(v0.x) + __bfloat162float(v1.x)
                + __bfloat162float(v2.x) + __bfloat162float(v3.x);
            a1 += __bfloat162float(v0.y) + __bfloat162float(v1.y)
                + __bfloat162float(v2.y) + __bfloat162float(v3.y);
        }
        for (; i < nch; ++i) {
            __hip_bfloat162 v = ((const __hip_bfloat162*)(M2 + (size_t)sl[i] * FEAT))[t];
            a0 += __bfloat162float(v.x);
            a1 += __bfloat162float(v.y);
        }
    }
    row[2 * t]     = a0;
    row[2 * t + 1] = a1;
    __syncthreads();
    #pragma unroll
    for (int gi = 0; gi < 2; ++gi) {
        int g = t + gi * 256;
        int m = (g < 384) ? ((g % 3) * 128 + g / 3) : g;
        out[(size_t)d * FEAT + g] += row[m];
    }
}

// =================================================================== launch
extern "C" void kernel_launch(void* const* d_in, const int* in_sizes, int n_in,
                              void* d_out, int out_size, void* d_ws, size_t ws_size,
                              hipStream_t stream) {
    (void)in_sizes; (void)n_in; (void)out_size; (void)ws_size;
    const float* x   = (const float*)d_in[0];
    const int*   ei  = (const int*)d_in[1];
    const float* ea1 = (const float*)d_in[2];
    const float* ea2 = (const float*)d_in[3];
    const float* W1  = (const float*)d_in[4];
    const float* b1  = (const float*)d_in[5];
    const float* W2  = (const float*)d_in[6];
    const float* b2  = (const float*)d_in[7];
    const float* W3  = (const float*)d_in[8];
    const float* b3  = (const float*)d_in[9];
    const float* U   = (const float*)d_in[10];
    const float* V   = (const float*)d_in[11];
    const float* Wu1 = (const float*)d_in[12];
    const float* bu1 = (const float*)d_in[13];
    const float* Wu2 = (const float*)d_in[14];
    const float* bu2 = (const float*)d_in[15];
    float* out = (float*)d_out;

    // ws layout (ws proven >= 165 MB in round 3; NEED ~= 40 MB)
    char* w = (char*)d_ws;
    __hip_bfloat16* Ab  = (__hip_bfloat16*)w;                       // N*384 bf16 = 7.68 MB
    __hip_bfloat16* xvp = (__hip_bfloat16*)(w + 7680000);           // N*384 bf16 = 7.68 MB
    __hip_bfloat16* M2  = (__hip_bfloat16*)(w + 15360000);          // N*512 bf16 = 10.24 MB
    float*          basis = (float*)(w + 25600000);                 // E*20 f32   = 12.8 MB
    int* offsets = (int*)(w + 38400000);                            // N+1
    int* count   = offsets + (N_NODES + 1);
    int* cursor  = count + N_NODES;
    int* bke     = cursor + N_NODES;
    int* bks     = bke + N_EDGES;

    k_zero_ints<<<(2 * N_NODES + 255) / 256,    256, 0, stream>>>(count, 2 * N_NODES);
    k_count    <<<(N_EDGES + 255) / 256,        256, 0, stream>>>(ei, count);
    k_scan     <<<1,                            256, 0, stream>>>(count, offsets);
    k_bin      <<<(N_EDGES + 255) / 256,        256, 0, stream>>>(ei, offsets, cursor, bke, bks);
    k_basis    <<<(N_EDGES * NRBF + 255) / 256, 256, 0, stream>>>(ea2, basis);

    k_A        <<<N_NODES / NPB1, 256, 0, stream>>>(x, W1, b1, W3, b3, Ab, xvp);
    k_gather1  <<<N_NODES,        128, 0, stream>>>(x, Ab, xvp, basis, ea1, W2, b2, offsets, bke, bks, out);
    k_B        <<<N_NODES / NPB2, 256, 0, stream>>>(U, V, Wu1, bu1, Wu2, bu2, out, M2);
    k_gather2  <<<N_NODES,        256, 0, stream>>>(M2, offsets, bks, out);
}

// Round 6
// 318.203 us; speedup vs baseline: 10.0155x; 1.3309x over previous
//
#include <hip/hip_runtime.h>
#include <hip/hip_bf16.h>

#define N_NODES 10000
#define N_EDGES 160000
#define FEAT 512
#define D 128
#define NRBF 20
#define RCUT 1.4415f

typedef __attribute__((ext_vector_type(8))) short bf16x8;
typedef __attribute__((ext_vector_type(4))) float f32x4;

__device__ __forceinline__ float silu_f(float x) { return x / (1.0f + __expf(-x)); }
__device__ __forceinline__ float s2f(short s) {
    unsigned int u = ((unsigned int)(unsigned short)s) << 16;
    float f; __builtin_memcpy(&f, &u, 4); return f;
}
__device__ __forceinline__ short f2s(float f) {
    __hip_bfloat16 h = __float2bfloat16(f);
    short s; __builtin_memcpy(&s, &h, 2); return s;
}

// ================================================================= CSR build
__global__ __launch_bounds__(256) void k_zero_ints(int* __restrict__ p, int n) {
    int i = blockIdx.x * blockDim.x + threadIdx.x;
    if (i < n) p[i] = 0;
}

__global__ __launch_bounds__(256) void k_count(const int* __restrict__ ei,
                                               int* __restrict__ count) {
    int e = blockIdx.x * blockDim.x + threadIdx.x;
    if (e < N_EDGES) atomicAdd(&count[ei[N_EDGES + e]], 1);
}

__global__ __launch_bounds__(256) void k_scan(const int* __restrict__ count,
                                              int* __restrict__ offsets) {
    __shared__ int sums[256];
    const int t = threadIdx.x;
    const int base = t * 40;
    int s = 0;
    for (int i = 0; i < 40; ++i) {
        int idx = base + i;
        if (idx < N_NODES) s += count[idx];
    }
    sums[t] = s;
    __syncthreads();
    for (int off = 1; off < 256; off <<= 1) {
        int v = (t >= off) ? sums[t - off] : 0;
        __syncthreads();
        sums[t] += v;
        __syncthreads();
    }
    int run = (t == 0) ? 0 : sums[t - 1];
    for (int i = 0; i < 40; ++i) {
        int idx = base + i;
        if (idx < N_NODES) { offsets[idx] = run; run += count[idx]; }
    }
    if (t == 255) offsets[N_NODES] = run;
}

__global__ __launch_bounds__(256) void k_bin(const int* __restrict__ ei,
                                             const int* __restrict__ offsets,
                                             int* __restrict__ cursor,
                                             int* __restrict__ bke,
                                             int* __restrict__ bks) {
    int e = blockIdx.x * blockDim.x + threadIdx.x;
    if (e < N_EDGES) {
        int d = ei[N_EDGES + e];
        int pos = offsets[d] + atomicAdd(&cursor[d], 1);
        bke[pos] = e;
        bks[pos] = ei[e];
    }
}

// ================================================================ k_basis (bf16)
__global__ __launch_bounds__(256) void k_basis(const float* __restrict__ ea2,
                                               __hip_bfloat16* __restrict__ basis) {
    int i = blockIdx.x * blockDim.x + threadIdx.x;
    if (i < N_EDGES * NRBF) {
        int e = i / NRBF, n = i % NRBF;
        float r  = ea2[e];
        float pr = 3.14159265358979f * r / RCUT;
        float rbf = sqrtf(2.0f / RCUT) * __sinf((float)(n + 1) * pr) / r;
        float cut = 0.5f * (__cosf(pr) + 1.0f) * (r < RCUT ? 1.0f : 0.0f);
        basis[i] = __float2bfloat16(rbf * cut);
    }
}

// ================================================================ k_pack
// Pack row-major KxN fp32 weight into B-fragment order:
// Wp[((ks*NT + ct)*64 + lane)*8 + j] = bf16(W[(ks*32 + (lane>>4)*8 + j)*N + ct*16 + (lane&15)])
__global__ __launch_bounds__(256) void k_pack(const float* __restrict__ W,
                                              short* __restrict__ Wp,
                                              int K, int N) {
    int idx = blockIdx.x * 256 + threadIdx.x;       // frag_id*64 + lane
    int NT = N >> 4;
    int total = (K >> 5) * NT * 64;
    if (idx >= total) return;
    int lane = idx & 63;
    int fid  = idx >> 6;
    int ks = fid / NT, ct = fid % NT;
    int k0 = ks * 32 + ((lane >> 4) << 3);
    int c  = ct * 16 + (lane & 15);
    short* o = Wp + (size_t)idx * 8;
    #pragma unroll
    for (int j = 0; j < 8; ++j)
        o[j] = f2s(W[(size_t)(k0 + j) * N + c]);
}

// ================================================================ k_A (MFMA)
// Ab[n][col] = (silu(x[n,384:]@W1+b1)@W3+b3)[col]  (bf16, col 0..383)
// xvp[n][c*128+j] = x[n][3j+c]  (bf16)
#define LDSP 136   // padded row stride (shorts): 272 B = 17*16 -> aligned b128, <=2-way banks
__global__ __launch_bounds__(256) void k_A_mfma(
    const float* __restrict__ x,
    const short* __restrict__ W1p, const float* __restrict__ b1,
    const short* __restrict__ W3p, const float* __restrict__ b3,
    __hip_bfloat16* __restrict__ Ab, __hip_bfloat16* __restrict__ xvp)
{
    __shared__ __align__(16) short sj[16 * LDSP];
    __shared__ __align__(16) short tt[16 * LDSP];
    const int t = threadIdx.x;
    const int lane = t & 63, wave = t >> 6;
    const int n0 = blockIdx.x * 16;

    for (int i = t; i < 16 * 128; i += 256) {
        int e = i >> 7, j = i & 127;
        sj[e * LDSP + j] = f2s(x[(size_t)(n0 + e) * FEAT + 384 + j]);
    }
    for (int i = t; i < 16 * 384; i += 256) {
        int e = i / 384, o = i % 384;
        int j = o & 127, c = o >> 7;
        xvp[(size_t)(n0 + e) * 384 + o] =
            __float2bfloat16(x[(size_t)(n0 + e) * FEAT + 3 * j + c]);
    }
    __syncthreads();

    // GEMM1: T = silu(sj @ W1 + b1)
    {
        f32x4 acc[2];
        #pragma unroll
        for (int q = 0; q < 2; ++q) acc[q] = (f32x4){0.f, 0.f, 0.f, 0.f};
        for (int ks = 0; ks < 4; ++ks) {
            bf16x8 a = *(const bf16x8*)&sj[(lane & 15) * LDSP + ks * 32 + ((lane >> 4) << 3)];
            #pragma unroll
            for (int q = 0; q < 2; ++q) {
                bf16x8 b = ((const bf16x8*)W1p)[((size_t)ks * 8 + wave * 2 + q) * 64 + lane];
                acc[q] = __builtin_amdgcn_mfma_f32_16x16x32_bf16(a, b, acc[q], 0, 0, 0);
            }
        }
        #pragma unroll
        for (int q = 0; q < 2; ++q) {
            int col = (wave * 2 + q) * 16 + (lane & 15);
            int row = (lane >> 4) << 2;
            float bb = b1[col];
            #pragma unroll
            for (int r = 0; r < 4; ++r)
                tt[(row + r) * LDSP + col] = f2s(silu_f(acc[q][r] + bb));
        }
    }
    __syncthreads();

    // GEMM2: A = T @ W3 + b3  (N = 384)
    {
        f32x4 acc[6];
        #pragma unroll
        for (int q = 0; q < 6; ++q) acc[q] = (f32x4){0.f, 0.f, 0.f, 0.f};
        for (int ks = 0; ks < 4; ++ks) {
            bf16x8 a = *(const bf16x8*)&tt[(lane & 15) * LDSP + ks * 32 + ((lane >> 4) << 3)];
            #pragma unroll
            for (int q = 0; q < 6; ++q) {
                bf16x8 b = ((const bf16x8*)W3p)[((size_t)ks * 24 + wave * 6 + q) * 64 + lane];
                acc[q] = __builtin_amdgcn_mfma_f32_16x16x32_bf16(a, b, acc[q], 0, 0, 0);
            }
        }
        #pragma unroll
        for (int q = 0; q < 6; ++q) {
            int col = (wave * 6 + q) * 16 + (lane & 15);
            int row = (lane >> 4) << 2;
            float bb = b3[col];
            #pragma unroll
            for (int r = 0; r < 4; ++r)
                Ab[(size_t)(n0 + row + r) * 384 + col] = __float2bfloat16(acc[q][r] + bb);
        }
    }
}

// ================================================================ k_B (MFMA)
// Per-node phase-2 message M2[n]: [c*128+j] = vu[j][c]*a1[j], [384+j] = dot+a3[j]
__global__ __launch_bounds__(256) void k_B_mfma(
    const short* __restrict__ Up, const short* __restrict__ Vp,
    const short* __restrict__ Wu1p, const float* __restrict__ bu1,
    const short* __restrict__ Wu2p, const float* __restrict__ bu2,
    const float* __restrict__ xin,
    __hip_bfloat16* __restrict__ M2)
{
    __shared__ __align__(16) short XV[48 * LDSP];   // v-part; holds VV after stage 2
    __shared__ __align__(16) short VU[48 * LDSP];
    __shared__ __align__(16) short S [16 * LDSP];
    __shared__ __align__(16) short NRM[16 * LDSP];
    __shared__ __align__(16) short H1[16 * LDSP];
    __shared__ __align__(16) short A1[16 * LDSP];
    __shared__ __align__(16) short A3[16 * LDSP];

    const int t = threadIdx.x, lane = t & 63, wave = t >> 6;
    const int n0 = blockIdx.x * 16;

    // stage 0: load 16 rows of xin
    for (int i = t; i < 16 * 512; i += 256) {
        int e = i >> 9, f = i & 511;
        short sv = f2s(xin[(size_t)(n0 + e) * FEAT + f]);
        if (f < 384) XV[(e * 3 + (f >> 7)) * LDSP + (f & 127)] = sv;
        else         S[e * LDSP + (f - 384)] = sv;
    }
    __syncthreads();

    // GEMM-U: VU = XV @ U   (48 x 128, K=128)
    {
        f32x4 acc[3][2];
        #pragma unroll
        for (int rt = 0; rt < 3; ++rt)
            #pragma unroll
            for (int q = 0; q < 2; ++q) acc[rt][q] = (f32x4){0.f, 0.f, 0.f, 0.f};
        for (int ks = 0; ks < 4; ++ks) {
            bf16x8 b[2];
            #pragma unroll
            for (int q = 0; q < 2; ++q)
                b[q] = ((const bf16x8*)Up)[((size_t)ks * 8 + wave * 2 + q) * 64 + lane];
            #pragma unroll
            for (int rt = 0; rt < 3; ++rt) {
                bf16x8 a = *(const bf16x8*)&XV[(rt * 16 + (lane & 15)) * LDSP + ks * 32 + ((lane >> 4) << 3)];
                #pragma unroll
                for (int q = 0; q < 2; ++q)
                    acc[rt][q] = __builtin_amdgcn_mfma_f32_16x16x32_bf16(a, b[q], acc[rt][q], 0, 0, 0);
            }
        }
        #pragma unroll
        for (int rt = 0; rt < 3; ++rt)
            #pragma unroll
            for (int q = 0; q < 2; ++q) {
                int col = (wave * 2 + q) * 16 + (lane & 15);
                int row = rt * 16 + ((lane >> 4) << 2);
                #pragma unroll
                for (int r = 0; r < 4; ++r)
                    VU[(row + r) * LDSP + col] = f2s(acc[rt][q][r]);
            }
    }
    __syncthreads();

    // GEMM-V: VV = VU @ V  -> stored into XV
    {
        f32x4 acc[3][2];
        #pragma unroll
        for (int rt = 0; rt < 3; ++rt)
            #pragma unroll
            for (int q = 0; q < 2; ++q) acc[rt][q] = (f32x4){0.f, 0.f, 0.f, 0.f};
        for (int ks = 0; ks < 4; ++ks) {
            bf16x8 b[2];
            #pragma unroll
            for (int q = 0; q < 2; ++q)
                b[q] = ((const bf16x8*)Vp)[((size_t)ks * 8 + wave * 2 + q) * 64 + lane];
            #pragma unroll
            for (int rt = 0; rt < 3; ++rt) {
                bf16x8 a = *(const bf16x8*)&VU[(rt * 16 + (lane & 15)) * LDSP + ks * 32 + ((lane >> 4) << 3)];
                #pragma unroll
                for (int q = 0; q < 2; ++q)
                    acc[rt][q] = __builtin_amdgcn_mfma_f32_16x16x32_bf16(a, b[q], acc[rt][q], 0, 0, 0);
            }
        }
        __syncthreads();   // all XV(A-source of GEMM-U) reads done before overwrite
        #pragma unroll
        for (int rt = 0; rt < 3; ++rt)
            #pragma unroll
            for (int q = 0; q < 2; ++q) {
                int col = (wave * 2 + q) * 16 + (lane & 15);
                int row = rt * 16 + ((lane >> 4) << 2);
                #pragma unroll
                for (int r = 0; r < 4; ++r)
                    XV[(row + r) * LDSP + col] = f2s(acc[rt][q][r]);
            }
    }
    __syncthreads();

    // NRM[nl][j] = || vv[nl][j][0..2] ||   (vv flat index q = 3j+c in the 384-vec)
    for (int i = t; i < 16 * 128; i += 256) {
        int nl = i >> 7, j = i & 127;
        float s = 0.f;
        #pragma unroll
        for (int c = 0; c < 3; ++c) {
            int q = 3 * j + c;
            float f = s2f(XV[(nl * 3 + (q >> 7)) * LDSP + (q & 127)]);
            s += f * f;
        }
        NRM[nl * LDSP + j] = f2s(sqrtf(s));
    }
    __syncthreads();

    // GEMM-Wu1: H1 = silu([NRM | S] @ Wu1 + bu1)   (K=256)
    {
        f32x4 acc[2];
        #pragma unroll
        for (int q = 0; q < 2; ++q) acc[q] = (f32x4){0.f, 0.f, 0.f, 0.f};
        for (int ks = 0; ks < 8; ++ks) {
            const short* asrc = (ks < 4) ? NRM : S;
            int k0 = (ks & 3) * 32;
            bf16x8 a = *(const bf16x8*)&asrc[(lane & 15) * LDSP + k0 + ((lane >> 4) << 3)];
            #pragma unroll
            for (int q = 0; q < 2; ++q) {
                bf16x8 b = ((const bf16x8*)Wu1p)[((size_t)ks * 8 + wave * 2 + q) * 64 + lane];
                acc[q] = __builtin_amdgcn_mfma_f32_16x16x32_bf16(a, b, acc[q], 0, 0, 0);
            }
        }
        #pragma unroll
        for (int q = 0; q < 2; ++q) {
            int col = (wave * 2 + q) * 16 + (lane & 15);
            int row = (lane >> 4) << 2;
            float bb = bu1[col];
            #pragma unroll
            for (int r = 0; r < 4; ++r)
                H1[(row + r) * LDSP + col] = f2s(silu_f(acc[q][r] + bb));
        }
    }
    __syncthreads();

    // GEMM-Wu2: A1 = H1@Wu2[:, :128] + bu2[:128]; A3 = H1@Wu2[:, 256:] + bu2[256:]
    {
        f32x4 acc[4];
        #pragma unroll
        for (int q = 0; q < 4; ++q) acc[q] = (f32x4){0.f, 0.f, 0.f, 0.f};
        for (int ks = 0; ks < 4; ++ks) {
            bf16x8 a = *(const bf16x8*)&H1[(lane & 15) * LDSP + ks * 32 + ((lane >> 4) << 3)];
            #pragma unroll
            for (int q = 0; q < 4; ++q) {
                int w = wave * 4 + q;                       // 0..15
                int ctp = (w < 8) ? w : (16 + (w - 8));     // Wu2 col-tile (N=384, NT=24)
                bf16x8 b = ((const bf16x8*)Wu2p)[((size_t)ks * 24 + ctp) * 64 + lane];
                acc[q] = __builtin_amdgcn_mfma_f32_16x16x32_bf16(a, b, acc[q], 0, 0, 0);
            }
        }
        #pragma unroll
        for (int q = 0; q < 4; ++q) {
            int w = wave * 4 + q;
            int colloc = (w & 7) * 16 + (lane & 15);
            int row = (lane >> 4) << 2;
            short* dst = (w < 8) ? A1 : A3;
            float bb = bu2[((w < 8) ? 0 : 256) + colloc];
            #pragma unroll
            for (int r = 0; r < 4; ++r)
                dst[(row + r) * LDSP + colloc] = f2s(acc[q][r] + bb);
        }
    }
    __syncthreads();

    // epilogue
    for (int i = t; i < 16 * 128; i += 256) {
        int nl = i >> 7, j = i & 127;
        float a1v = s2f(A1[nl * LDSP + j]);
        float a3v = s2f(A3[nl * LDSP + j]);
        __hip_bfloat16* mrow = M2 + (size_t)(n0 + nl) * FEAT;
        float dot = 0.f;
        #pragma unroll
        for (int c = 0; c < 3; ++c) {
            int q = 3 * j + c;
            int rr = nl * 3 + (q >> 7), cc = q & 127;
            float vu_ = s2f(VU[rr * LDSP + cc]);
            float vv_ = s2f(XV[rr * LDSP + cc]);
            float vf = vu_ * a1v;
            dot += vf * vv_;
            mrow[c * 128 + j] = __float2bfloat16(vf);
        }
        mrow[384 + j] = __float2bfloat16(dot + a3v);
    }
}

// ================================================================ k_gather1
#define CH 8
__global__ __launch_bounds__(128) void k_gather1(
    const float* __restrict__ x,
    const __hip_bfloat16* __restrict__ Ab,
    const __hip_bfloat16* __restrict__ xvp,
    const __hip_bfloat16* __restrict__ basis,
    const float* __restrict__ ea1,
    const float* __restrict__ W2, const float* __restrict__ b2,
    const int* __restrict__ offsets,
    const int* __restrict__ bke, const int* __restrict__ bks,
    float* __restrict__ out)
{
    __shared__ float ebl[CH][NRBF];
    __shared__ float eall[CH][3];
    __shared__ int srcl[CH], ekl[CH];

    const int d = blockIdx.x, t = threadIdx.x;

    float w2r0[NRBF], w2r1[NRBF], w2r2[NRBF];
    #pragma unroll
    for (int n = 0; n < NRBF; ++n) {
        w2r0[n] = W2[n * 384 + t];
        w2r1[n] = W2[n * 384 + 128 + t];
        w2r2[n] = W2[n * 384 + 256 + t];
    }
    const float b2a = b2[t], b2b = b2[128 + t], b2c = b2[256 + t];

    float acc0 = 0.f, acc1 = 0.f, acc2 = 0.f, accs = 0.f;
    const int o0 = offsets[d], o1 = offsets[d + 1];

    for (int bi = o0; bi < o1; bi += CH) {
        __syncthreads();
        if (t < CH) {
            int idx = bi + t; if (idx >= o1) idx = o0;
            srcl[t] = bks[idx]; ekl[t] = bke[idx];
        }
        __syncthreads();
        for (int i = t; i < CH * NRBF; i += 128)
            ebl[i / NRBF][i % NRBF] = __bfloat162float(basis[(size_t)ekl[i / NRBF] * NRBF + (i % NRBF)]);
        if (t < CH * 3) eall[t / 3][t % 3] = ea1[(size_t)ekl[t / 3] * 3 + (t % 3)];
        __syncthreads();

        float av[CH][3], xv[CH][3];
        #pragma unroll
        for (int ee = 0; ee < CH; ++ee) {
            const size_t s = (size_t)srcl[ee];
            const __hip_bfloat16* Ar = Ab + s * 384;
            const __hip_bfloat16* Xr = xvp + s * 384;
            av[ee][0] = __bfloat162float(Ar[t]);
            av[ee][1] = __bfloat162float(Ar[128 + t]);
            av[ee][2] = __bfloat162float(Ar[256 + t]);
            xv[ee][0] = __bfloat162float(Xr[t]);
            xv[ee][1] = __bfloat162float(Xr[128 + t]);
            xv[ee][2] = __bfloat162float(Xr[256 + t]);
        }

        #pragma unroll
        for (int ee = 0; ee < CH; ++ee) {
            float vm = (bi + ee < o1) ? 1.0f : 0.0f;
            float ebA = b2a, ebB = b2b, ebC = b2c;
            #pragma unroll
            for (int n = 0; n < NRBF; ++n) {
                float e = ebl[ee][n];
                ebA += e * w2r0[n];
                ebB += e * w2r1[n];
                ebC += e * w2r2[n];
            }
            float s1 = av[ee][0] * ebA;
            float s2 = av[ee][1] * ebB;
            float s3 = av[ee][2] * ebC;
            acc0 += vm * (xv[ee][0] * s1 + s3 * eall[ee][0]);
            acc1 += vm * (xv[ee][1] * s1 + s3 * eall[ee][1]);
            acc2 += vm * (xv[ee][2] * s1 + s3 * eall[ee][2]);
            accs += vm * s2;
        }
    }

    const size_t ro = (size_t)d * FEAT;
    out[ro + 3 * t]     = x[ro + 3 * t]     + acc0;
    out[ro + 3 * t + 1] = x[ro + 3 * t + 1] + acc1;
    out[ro + 3 * t + 2] = x[ro + 3 * t + 2] + acc2;
    out[ro + 384 + t]   = x[ro + 384 + t]   + accs;
}

// ================================================================ k_gather2
__global__ __launch_bounds__(256) void k_gather2(
    const __hip_bfloat16* __restrict__ M2,
    const int* __restrict__ offsets,
    const int* __restrict__ bks,
    float* __restrict__ out)
{
    __shared__ float row[FEAT];
    __shared__ int sl[32];
    const int d = blockIdx.x, t = threadIdx.x;
    const int o0 = offsets[d], o1 = offsets[d + 1];
    float a0 = 0.0f, a1 = 0.0f;
    for (int bi = o0; bi < o1; bi += 32) {
        int nch = min(32, o1 - bi);
        __syncthreads();
        if (t < nch) sl[t] = bks[bi + t];
        __syncthreads();
        int i = 0;
        for (; i + 4 <= nch; i += 4) {
            __hip_bfloat162 v0 = ((const __hip_bfloat162*)(M2 + (size_t)sl[i]     * FEAT))[t];
            __hip_bfloat162 v1 = ((const __hip_bfloat162*)(M2 + (size_t)sl[i + 1] * FEAT))[t];
            __hip_bfloat162 v2 = ((const __hip_bfloat162*)(M2 + (size_t)sl[i + 2] * FEAT))[t];
            __hip_bfloat162 v3 = ((const __hip_bfloat162*)(M2 + (size_t)sl[i + 3] * FEAT))[t];
            a0 += __bfloat162float(v0.x) + __bfloat162float(v1.x)
                + __bfloat162float(v2.x) + __bfloat162float(v3.x);
            a1 += __bfloat162float(v0.y) + __bfloat162float(v1.y)
                + __bfloat162float(v2.y) + __bfloat162float(v3.y);
        }
        for (; i < nch; ++i) {
            __hip_bfloat162 v = ((const __hip_bfloat162*)(M2 + (size_t)sl[i] * FEAT))[t];
            a0 += __bfloat162float(v.x);
            a1 += __bfloat162float(v.y);
        }
    }
    row[2 * t]     = a0;
    row[2 * t + 1] = a1;
    __syncthreads();
    #pragma unroll
    for (int gi = 0; gi < 2; ++gi) {
        int g = t + gi * 256;
        int m = (g < 384) ? ((g % 3) * 128 + g / 3) : g;
        out[(size_t)d * FEAT + g] += row[m];
    }
}

// =================================================================== launch
extern "C" void kernel_launch(void* const* d_in, const int* in_sizes, int n_in,
                              void* d_out, int out_size, void* d_ws, size_t ws_size,
                              hipStream_t stream) {
    (void)in_sizes; (void)n_in; (void)out_size; (void)ws_size;
    const float* x   = (const float*)d_in[0];
    const int*   ei  = (const int*)d_in[1];
    const float* ea1 = (const float*)d_in[2];
    const float* ea2 = (const float*)d_in[3];
    const float* W1  = (const float*)d_in[4];
    const float* b1  = (const float*)d_in[5];
    const float* W2  = (const float*)d_in[6];
    const float* b2  = (const float*)d_in[7];
    const float* W3  = (const float*)d_in[8];
    const float* b3  = (const float*)d_in[9];
    const float* U   = (const float*)d_in[10];
    const float* V   = (const float*)d_in[11];
    const float* Wu1 = (const float*)d_in[12];
    const float* bu1 = (const float*)d_in[13];
    const float* Wu2 = (const float*)d_in[14];
    const float* bu2 = (const float*)d_in[15];
    float* out = (float*)d_out;

    // ws layout (proven >= 39.8 MB in round 3; used here <= ~33.8 MB)
    char* w = (char*)d_ws;
    __hip_bfloat16* Ab    = (__hip_bfloat16*)w;                 //  7,680,000
    __hip_bfloat16* xvp   = (__hip_bfloat16*)(w + 7680000);     //  7,680,000
    __hip_bfloat16* M2    = (__hip_bfloat16*)(w + 15360000);    // 10,240,000
    __hip_bfloat16* basis = (__hip_bfloat16*)(w + 25600000);    //  6,400,000 (bf16)
    short* W1p  = (short*)(w + 32000000);                       //  32,768 B
    short* W3p  = (short*)(w + 32032768);                       //  98,304 B
    short* Upk  = (short*)(w + 32131072);                       //  32,768 B
    short* Vpk  = (short*)(w + 32163840);                       //  32,768 B
    short* Wu1p = (short*)(w + 32196608);                       //  65,536 B
    short* Wu2p = (short*)(w + 32262144);                       //  98,304 B
    int* offsets = (int*)(w + 32360448);
    int* count   = offsets + (N_NODES + 1);
    int* cursor  = count + N_NODES;
    int* bke     = cursor + N_NODES;
    int* bks     = bke + N_EDGES;

    // weight packing (tiny)
    k_pack<<<8,  256, 0, stream>>>(W1,  W1p,  128, 128);
    k_pack<<<24, 256, 0, stream>>>(W3,  W3p,  128, 384);
    k_pack<<<8,  256, 0, stream>>>(U,   Upk,  128, 128);
    k_pack<<<8,  256, 0, stream>>>(V,   Vpk,  128, 128);
    k_pack<<<16, 256, 0, stream>>>(Wu1, Wu1p, 256, 128);
    k_pack<<<24, 256, 0, stream>>>(Wu2, Wu2p, 128, 384);

    k_zero_ints<<<(2 * N_NODES + 255) / 256,    256, 0, stream>>>(count, 2 * N_NODES);
    k_count    <<<(N_EDGES + 255) / 256,        256, 0, stream>>>(ei, count);
    k_scan     <<<1,                            256, 0, stream>>>(count, offsets);
    k_bin      <<<(N_EDGES + 255) / 256,        256, 0, stream>>>(ei, offsets, cursor, bke, bks);
    k_basis    <<<(N_EDGES * NRBF + 255) / 256, 256, 0, stream>>>(ea2, basis);

    k_A_mfma   <<<N_NODES / 16, 256, 0, stream>>>(x, W1p, b1, W3p, b3, Ab, xvp);
    k_gather1  <<<N_NODES,      128, 0, stream>>>(x, Ab, xvp, basis, ea1, W2, b2, offsets, bke, bks, out);
    k_B_mfma   <<<N_NODES / 16, 256, 0, stream>>>(Upk, Vpk, Wu1p, bu1, Wu2p, bu2, out, M2);
    k_gather2  <<<N_NODES,      256, 0, stream>>>(M2, offsets, bks, out);
}

// Round 7
// 256.086 us; speedup vs baseline: 12.4449x; 1.2426x over previous
//
#include <hip/hip_runtime.h>
#include <hip/hip_bf16.h>

#define N_NODES 10000
#define N_EDGES 160000
#define FEAT 512
#define D 128
#define NRBF 20
#define RCUT 1.4415f
#define CAP 64          // max degree bucket capacity (Poisson(16): P(deg>64) ~ 1e-20)

typedef __attribute__((ext_vector_type(8))) short bf16x8;
typedef __attribute__((ext_vector_type(4))) float f32x4;

__device__ __forceinline__ float silu_f(float x) { return x / (1.0f + __expf(-x)); }
__device__ __forceinline__ float s2f(short s) {
    unsigned int u = ((unsigned int)(unsigned short)s) << 16;
    float f; __builtin_memcpy(&f, &u, 4); return f;
}
__device__ __forceinline__ short f2s(float f) {
    __hip_bfloat16 h = __float2bfloat16(f);
    short s; __builtin_memcpy(&s, &h, 2); return s;
}

// ================================================================ CSR (bucketed)
__global__ __launch_bounds__(256) void k_zero_ints(int* __restrict__ p, int n) {
    int i = blockIdx.x * blockDim.x + threadIdx.x;
    if (i < n) p[i] = 0;
}

// slot[d*CAP + pos] = (e << 14) | src   (e < 2^18, src < 2^14, unsigned)
__global__ __launch_bounds__(256) void k_fill(const int* __restrict__ ei,
                                              int* __restrict__ cnt,
                                              unsigned int* __restrict__ slot) {
    int e = blockIdx.x * blockDim.x + threadIdx.x;
    if (e < N_EDGES) {
        int d = ei[N_EDGES + e];
        int pos = atomicAdd(&cnt[d], 1);
        if (pos < CAP)
            slot[d * CAP + pos] = (((unsigned int)e) << 14) | (unsigned int)ei[e];
    }
}

// ================================================================ k_basis (bf16)
__global__ __launch_bounds__(256) void k_basis(const float* __restrict__ ea2,
                                               __hip_bfloat16* __restrict__ basis) {
    int i = blockIdx.x * blockDim.x + threadIdx.x;
    if (i < N_EDGES * NRBF) {
        int e = i / NRBF, n = i % NRBF;
        float r  = ea2[e];
        float pr = 3.14159265358979f * r / RCUT;
        float rbf = sqrtf(2.0f / RCUT) * __sinf((float)(n + 1) * pr) / r;
        float cut = 0.5f * (__cosf(pr) + 1.0f) * (r < RCUT ? 1.0f : 0.0f);
        basis[i] = __float2bfloat16(rbf * cut);
    }
}

// ================================================================ k_pack
// Wp[((ks*NT + ct)*64 + lane)*8 + j] = bf16(W[(ks*32 + (lane>>4)*8 + j)*N + ct*16 + (lane&15)])
__global__ __launch_bounds__(256) void k_pack(const float* __restrict__ W,
                                              short* __restrict__ Wp,
                                              int K, int N) {
    int idx = blockIdx.x * 256 + threadIdx.x;
    int NT = N >> 4;
    int total = (K >> 5) * NT * 64;
    if (idx >= total) return;
    int lane = idx & 63;
    int fid  = idx >> 6;
    int ks = fid / NT, ct = fid % NT;
    int k0 = ks * 32 + ((lane >> 4) << 3);
    int c  = ct * 16 + (lane & 15);
    short* o = Wp + (size_t)idx * 8;
    #pragma unroll
    for (int j = 0; j < 8; ++j)
        o[j] = f2s(W[(size_t)(k0 + j) * N + c]);
}

// ================================================================ k_A (MFMA)
// P1 row (768 bf16): [0..383] = A = silu(xs@W1+b1)@W3+b3, [384+c*128+j] = x[n][3j+c]
#define LDSP 136
__global__ __launch_bounds__(256) void k_A_mfma(
    const float* __restrict__ x,
    const short* __restrict__ W1p, const float* __restrict__ b1,
    const short* __restrict__ W3p, const float* __restrict__ b3,
    __hip_bfloat16* __restrict__ P1)
{
    __shared__ __align__(16) short sj[16 * LDSP];
    __shared__ __align__(16) short tt[16 * LDSP];
    const int t = threadIdx.x;
    const int lane = t & 63, wave = t >> 6;
    const int n0 = blockIdx.x * 16;

    for (int i = t; i < 16 * 128; i += 256) {
        int e = i >> 7, j = i & 127;
        sj[e * LDSP + j] = f2s(x[(size_t)(n0 + e) * FEAT + 384 + j]);
    }
    // xvp pack into P1[:, 384:768]
    for (int i = t; i < 16 * 384; i += 256) {
        int e = i / 384, o = i % 384;
        int j = o & 127, c = o >> 7;
        P1[(size_t)(n0 + e) * 768 + 384 + o] =
            __float2bfloat16(x[(size_t)(n0 + e) * FEAT + 3 * j + c]);
    }
    __syncthreads();

    // GEMM1: T = silu(sj @ W1 + b1)
    {
        f32x4 acc[2];
        #pragma unroll
        for (int q = 0; q < 2; ++q) acc[q] = (f32x4){0.f, 0.f, 0.f, 0.f};
        for (int ks = 0; ks < 4; ++ks) {
            bf16x8 a = *(const bf16x8*)&sj[(lane & 15) * LDSP + ks * 32 + ((lane >> 4) << 3)];
            #pragma unroll
            for (int q = 0; q < 2; ++q) {
                bf16x8 b = ((const bf16x8*)W1p)[((size_t)ks * 8 + wave * 2 + q) * 64 + lane];
                acc[q] = __builtin_amdgcn_mfma_f32_16x16x32_bf16(a, b, acc[q], 0, 0, 0);
            }
        }
        #pragma unroll
        for (int q = 0; q < 2; ++q) {
            int col = (wave * 2 + q) * 16 + (lane & 15);
            int row = (lane >> 4) << 2;
            float bb = b1[col];
            #pragma unroll
            for (int r = 0; r < 4; ++r)
                tt[(row + r) * LDSP + col] = f2s(silu_f(acc[q][r] + bb));
        }
    }
    __syncthreads();

    // GEMM2: A = T @ W3 + b3 -> P1[:, 0:384]
    {
        f32x4 acc[6];
        #pragma unroll
        for (int q = 0; q < 6; ++q) acc[q] = (f32x4){0.f, 0.f, 0.f, 0.f};
        for (int ks = 0; ks < 4; ++ks) {
            bf16x8 a = *(const bf16x8*)&tt[(lane & 15) * LDSP + ks * 32 + ((lane >> 4) << 3)];
            #pragma unroll
            for (int q = 0; q < 6; ++q) {
                bf16x8 b = ((const bf16x8*)W3p)[((size_t)ks * 24 + wave * 6 + q) * 64 + lane];
                acc[q] = __builtin_amdgcn_mfma_f32_16x16x32_bf16(a, b, acc[q], 0, 0, 0);
            }
        }
        #pragma unroll
        for (int q = 0; q < 6; ++q) {
            int col = (wave * 6 + q) * 16 + (lane & 15);
            int row = (lane >> 4) << 2;
            float bb = b3[col];
            #pragma unroll
            for (int r = 0; r < 4; ++r)
                P1[(size_t)(n0 + row + r) * 768 + col] = __float2bfloat16(acc[q][r] + bb);
        }
    }
}

// ================================================================ k_B (MFMA)
__global__ __launch_bounds__(256) void k_B_mfma(
    const short* __restrict__ Up, const short* __restrict__ Vp,
    const short* __restrict__ Wu1p, const float* __restrict__ bu1,
    const short* __restrict__ Wu2p, const float* __restrict__ bu2,
    const float* __restrict__ xin,
    __hip_bfloat16* __restrict__ M2)
{
    __shared__ __align__(16) short XV[48 * LDSP];
    __shared__ __align__(16) short VU[48 * LDSP];
    __shared__ __align__(16) short S [16 * LDSP];
    __shared__ __align__(16) short NRM[16 * LDSP];
    __shared__ __align__(16) short H1[16 * LDSP];
    __shared__ __align__(16) short A1[16 * LDSP];
    __shared__ __align__(16) short A3[16 * LDSP];

    const int t = threadIdx.x, lane = t & 63, wave = t >> 6;
    const int n0 = blockIdx.x * 16;

    for (int i = t; i < 16 * 512; i += 256) {
        int e = i >> 9, f = i & 511;
        short sv = f2s(xin[(size_t)(n0 + e) * FEAT + f]);
        if (f < 384) XV[(e * 3 + (f >> 7)) * LDSP + (f & 127)] = sv;
        else         S[e * LDSP + (f - 384)] = sv;
    }
    __syncthreads();

    // GEMM-U: VU = XV @ U
    {
        f32x4 acc[3][2];
        #pragma unroll
        for (int rt = 0; rt < 3; ++rt)
            #pragma unroll
            for (int q = 0; q < 2; ++q) acc[rt][q] = (f32x4){0.f, 0.f, 0.f, 0.f};
        for (int ks = 0; ks < 4; ++ks) {
            bf16x8 b[2];
            #pragma unroll
            for (int q = 0; q < 2; ++q)
                b[q] = ((const bf16x8*)Up)[((size_t)ks * 8 + wave * 2 + q) * 64 + lane];
            #pragma unroll
            for (int rt = 0; rt < 3; ++rt) {
                bf16x8 a = *(const bf16x8*)&XV[(rt * 16 + (lane & 15)) * LDSP + ks * 32 + ((lane >> 4) << 3)];
                #pragma unroll
                for (int q = 0; q < 2; ++q)
                    acc[rt][q] = __builtin_amdgcn_mfma_f32_16x16x32_bf16(a, b[q], acc[rt][q], 0, 0, 0);
            }
        }
        #pragma unroll
        for (int rt = 0; rt < 3; ++rt)
            #pragma unroll
            for (int q = 0; q < 2; ++q) {
                int col = (wave * 2 + q) * 16 + (lane & 15);
                int row = rt * 16 + ((lane >> 4) << 2);
                #pragma unroll
                for (int r = 0; r < 4; ++r)
                    VU[(row + r) * LDSP + col] = f2s(acc[rt][q][r]);
            }
    }
    __syncthreads();

    // GEMM-V: VV = VU @ V -> XV
    {
        f32x4 acc[3][2];
        #pragma unroll
        for (int rt = 0; rt < 3; ++rt)
            #pragma unroll
            for (int q = 0; q < 2; ++q) acc[rt][q] = (f32x4){0.f, 0.f, 0.f, 0.f};
        for (int ks = 0; ks < 4; ++ks) {
            bf16x8 b[2];
            #pragma unroll
            for (int q = 0; q < 2; ++q)
                b[q] = ((const bf16x8*)Vp)[((size_t)ks * 8 + wave * 2 + q) * 64 + lane];
            #pragma unroll
            for (int rt = 0; rt < 3; ++rt) {
                bf16x8 a = *(const bf16x8*)&VU[(rt * 16 + (lane & 15)) * LDSP + ks * 32 + ((lane >> 4) << 3)];
                #pragma unroll
                for (int q = 0; q < 2; ++q)
                    acc[rt][q] = __builtin_amdgcn_mfma_f32_16x16x32_bf16(a, b[q], acc[rt][q], 0, 0, 0);
            }
        }
        __syncthreads();
        #pragma unroll
        for (int rt = 0; rt < 3; ++rt)
            #pragma unroll
            for (int q = 0; q < 2; ++q) {
                int col = (wave * 2 + q) * 16 + (lane & 15);
                int row = rt * 16 + ((lane >> 4) << 2);
                #pragma unroll
                for (int r = 0; r < 4; ++r)
                    XV[(row + r) * LDSP + col] = f2s(acc[rt][q][r]);
            }
    }
    __syncthreads();

    for (int i = t; i < 16 * 128; i += 256) {
        int nl = i >> 7, j = i & 127;
        float s = 0.f;
        #pragma unroll
        for (int c = 0; c < 3; ++c) {
            int q = 3 * j + c;
            float f = s2f(XV[(nl * 3 + (q >> 7)) * LDSP + (q & 127)]);
            s += f * f;
        }
        NRM[nl * LDSP + j] = f2s(sqrtf(s));
    }
    __syncthreads();

    // GEMM-Wu1: H1 = silu([NRM | S] @ Wu1 + bu1)
    {
        f32x4 acc[2];
        #pragma unroll
        for (int q = 0; q < 2; ++q) acc[q] = (f32x4){0.f, 0.f, 0.f, 0.f};
        for (int ks = 0; ks < 8; ++ks) {
            const short* asrc = (ks < 4) ? NRM : S;
            int k0 = (ks & 3) * 32;
            bf16x8 a = *(const bf16x8*)&asrc[(lane & 15) * LDSP + k0 + ((lane >> 4) << 3)];
            #pragma unroll
            for (int q = 0; q < 2; ++q) {
                bf16x8 b = ((const bf16x8*)Wu1p)[((size_t)ks * 8 + wave * 2 + q) * 64 + lane];
                acc[q] = __builtin_amdgcn_mfma_f32_16x16x32_bf16(a, b, acc[q], 0, 0, 0);
            }
        }
        #pragma unroll
        for (int q = 0; q < 2; ++q) {
            int col = (wave * 2 + q) * 16 + (lane & 15);
            int row = (lane >> 4) << 2;
            float bb = bu1[col];
            #pragma unroll
            for (int r = 0; r < 4; ++r)
                H1[(row + r) * LDSP + col] = f2s(silu_f(acc[q][r] + bb));
        }
    }
    __syncthreads();

    // GEMM-Wu2: A1 / A3 tiles
    {
        f32x4 acc[4];
        #pragma unroll
        for (int q = 0; q < 4; ++q) acc[q] = (f32x4){0.f, 0.f, 0.f, 0.f};
        for (int ks = 0; ks < 4; ++ks) {
            bf16x8 a = *(const bf16x8*)&H1[(lane & 15) * LDSP + ks * 32 + ((lane >> 4) << 3)];
            #pragma unroll
            for (int q = 0; q < 4; ++q) {
                int w = wave * 4 + q;
                int ctp = (w < 8) ? w : (16 + (w - 8));
                bf16x8 b = ((const bf16x8*)Wu2p)[((size_t)ks * 24 + ctp) * 64 + lane];
                acc[q] = __builtin_amdgcn_mfma_f32_16x16x32_bf16(a, b, acc[q], 0, 0, 0);
            }
        }
        #pragma unroll
        for (int q = 0; q < 4; ++q) {
            int w = wave * 4 + q;
            int colloc = (w & 7) * 16 + (lane & 15);
            int row = (lane >> 4) << 2;
            short* dst = (w < 8) ? A1 : A3;
            float bb = bu2[((w < 8) ? 0 : 256) + colloc];
            #pragma unroll
            for (int r = 0; r < 4; ++r)
                dst[(row + r) * LDSP + colloc] = f2s(acc[q][r] + bb);
        }
    }
    __syncthreads();

    for (int i = t; i < 16 * 128; i += 256) {
        int nl = i >> 7, j = i & 127;
        float a1v = s2f(A1[nl * LDSP + j]);
        float a3v = s2f(A3[nl * LDSP + j]);
        __hip_bfloat16* mrow = M2 + (size_t)(n0 + nl) * FEAT;
        float dot = 0.f;
        #pragma unroll
        for (int c = 0; c < 3; ++c) {
            int q = 3 * j + c;
            int rr = nl * 3 + (q >> 7), cc = q & 127;
            float vu_ = s2f(VU[rr * LDSP + cc]);
            float vv_ = s2f(XV[rr * LDSP + cc]);
            float vf = vu_ * a1v;
            dot += vf * vv_;
            mrow[c * 128 + j] = __float2bfloat16(vf);
        }
        mrow[384 + j] = __float2bfloat16(dot + a3v);
    }
}

// ================================================================ k_gather1
// out[d] = x[d] + sum_{e in bucket[d]} msg(e). One staging sync per node.
__global__ __launch_bounds__(128) void k_gather1(
    const float* __restrict__ x,
    const __hip_bfloat16* __restrict__ P1,
    const __hip_bfloat16* __restrict__ basis,
    const float* __restrict__ ea1,
    const float* __restrict__ W2, const float* __restrict__ b2,
    const int* __restrict__ cnt, const unsigned int* __restrict__ slot,
    float* __restrict__ out)
{
    __shared__ float ebl[CAP][NRBF];
    __shared__ float eall[CAP][3];
    __shared__ int srcl[CAP], ell[CAP];

    const int d = blockIdx.x, t = threadIdx.x;   // 128 threads

    float w2r0[NRBF], w2r1[NRBF], w2r2[NRBF];
    #pragma unroll
    for (int n = 0; n < NRBF; ++n) {
        w2r0[n] = W2[n * 384 + t];
        w2r1[n] = W2[n * 384 + 128 + t];
        w2r2[n] = W2[n * 384 + 256 + t];
    }
    const float b2a = b2[t], b2b = b2[128 + t], b2c = b2[256 + t];

    const int deg = min(cnt[d], CAP);
    if (t < deg) {
        unsigned int p = slot[d * CAP + t];
        srcl[t] = (int)(p & 16383u);
        ell[t]  = (int)(p >> 14);
    }
    __syncthreads();
    for (int i = t; i < deg * NRBF; i += 128)
        ebl[i / NRBF][i % NRBF] = __bfloat162float(basis[(size_t)ell[i / NRBF] * NRBF + (i % NRBF)]);
    for (int i = t; i < deg * 3; i += 128)
        eall[i / 3][i % 3] = ea1[(size_t)ell[i / 3] * 3 + (i % 3)];
    __syncthreads();

    float acc0 = 0.f, acc1 = 0.f, acc2 = 0.f, accs = 0.f;

    for (int base = 0; base < deg; base += 8) {
        // batch-load fragments for up to 8 edges (independent loads, one row stream)
        float fr[8][6];
        #pragma unroll
        for (int ee = 0; ee < 8; ++ee) {
            int idx = (base + ee < deg) ? (base + ee) : base;
            const __hip_bfloat16* R = P1 + (size_t)srcl[idx] * 768;
            fr[ee][0] = __bfloat162float(R[t]);          // A s1-col
            fr[ee][1] = __bfloat162float(R[128 + t]);    // A s2-col
            fr[ee][2] = __bfloat162float(R[256 + t]);    // A s3-col
            fr[ee][3] = __bfloat162float(R[384 + t]);    // xv c0
            fr[ee][4] = __bfloat162float(R[512 + t]);    // xv c1
            fr[ee][5] = __bfloat162float(R[640 + t]);    // xv c2
        }
        #pragma unroll
        for (int ee = 0; ee < 8; ++ee) {
            if (base + ee >= deg) break;                 // uniform per block
            const int ix = base + ee;
            float ebA = b2a, ebB = b2b, ebC = b2c;
            #pragma unroll
            for (int n = 0; n < NRBF; ++n) {
                float e = ebl[ix][n];
                ebA += e * w2r0[n];
                ebB += e * w2r1[n];
                ebC += e * w2r2[n];
            }
            float s1 = fr[ee][0] * ebA;
            float s2 = fr[ee][1] * ebB;
            float s3 = fr[ee][2] * ebC;
            acc0 += fr[ee][3] * s1 + s3 * eall[ix][0];
            acc1 += fr[ee][4] * s1 + s3 * eall[ix][1];
            acc2 += fr[ee][5] * s1 + s3 * eall[ix][2];
            accs += s2;
        }
    }

    const size_t ro = (size_t)d * FEAT;
    out[ro + 3 * t]     = x[ro + 3 * t]     + acc0;
    out[ro + 3 * t + 1] = x[ro + 3 * t + 1] + acc1;
    out[ro + 3 * t + 2] = x[ro + 3 * t + 2] + acc2;
    out[ro + 384 + t]   = x[ro + 384 + t]   + accs;
}

// ================================================================ k_gather2
__global__ __launch_bounds__(256) void k_gather2(
    const __hip_bfloat16* __restrict__ M2,
    const int* __restrict__ cnt, const unsigned int* __restrict__ slot,
    float* __restrict__ out)
{
    __shared__ float row[FEAT];
    __shared__ int sl[CAP];
    const int d = blockIdx.x, t = threadIdx.x;
    const int deg = min(cnt[d], CAP);
    if (t < deg) sl[t] = (int)(slot[d * CAP + t] & 16383u);
    __syncthreads();

    float a0 = 0.0f, a1 = 0.0f;
    int i = 0;
    for (; i + 8 <= deg; i += 8) {
        __hip_bfloat162 v[8];
        #pragma unroll
        for (int q = 0; q < 8; ++q)
            v[q] = ((const __hip_bfloat162*)(M2 + (size_t)sl[i + q] * FEAT))[t];
        #pragma unroll
        for (int q = 0; q < 8; ++q) {
            a0 += __bfloat162float(v[q].x);
            a1 += __bfloat162float(v[q].y);
        }
    }
    for (; i < deg; ++i) {
        __hip_bfloat162 v = ((const __hip_bfloat162*)(M2 + (size_t)sl[i] * FEAT))[t];
        a0 += __bfloat162float(v.x);
        a1 += __bfloat162float(v.y);
    }
    row[2 * t]     = a0;
    row[2 * t + 1] = a1;
    __syncthreads();
    #pragma unroll
    for (int gi = 0; gi < 2; ++gi) {
        int g = t + gi * 256;
        int m = (g < 384) ? ((g % 3) * 128 + g / 3) : g;
        out[(size_t)d * FEAT + g] += row[m];
    }
}

// =================================================================== launch
extern "C" void kernel_launch(void* const* d_in, const int* in_sizes, int n_in,
                              void* d_out, int out_size, void* d_ws, size_t ws_size,
                              hipStream_t stream) {
    (void)in_sizes; (void)n_in; (void)out_size; (void)ws_size;
    const float* x   = (const float*)d_in[0];
    const int*   ei  = (const int*)d_in[1];
    const float* ea1 = (const float*)d_in[2];
    const float* ea2 = (const float*)d_in[3];
    const float* W1  = (const float*)d_in[4];
    const float* b1  = (const float*)d_in[5];
    const float* W2  = (const float*)d_in[6];
    const float* b2  = (const float*)d_in[7];
    const float* W3  = (const float*)d_in[8];
    const float* b3  = (const float*)d_in[9];
    const float* U   = (const float*)d_in[10];
    const float* V   = (const float*)d_in[11];
    const float* Wu1 = (const float*)d_in[12];
    const float* bu1 = (const float*)d_in[13];
    const float* Wu2 = (const float*)d_in[14];
    const float* bu2 = (const float*)d_in[15];
    float* out = (float*)d_out;

    // ws layout (proven >= 39.8 MB; used ~35 MB)
    char* w = (char*)d_ws;
    __hip_bfloat16* P1    = (__hip_bfloat16*)w;                 // N*768 bf16 = 15,360,000
    __hip_bfloat16* M2    = (__hip_bfloat16*)(w + 15360000);    // N*512 bf16 = 10,240,000
    __hip_bfloat16* basis = (__hip_bfloat16*)(w + 25600000);    // E*20 bf16  =  6,400,000
    short* W1p  = (short*)(w + 32000000);
    short* W3p  = (short*)(w + 32032768);
    short* Upk  = (short*)(w + 32131072);
    short* Vpk  = (short*)(w + 32163840);
    short* Wu1p = (short*)(w + 32196608);
    short* Wu2p = (short*)(w + 32262144);
    int*          cnt  = (int*)(w + 32360448);                  // N ints
    unsigned int* slot = (unsigned int*)(w + 32400448);         // N*CAP uints

    k_pack<<<8,  256, 0, stream>>>(W1,  W1p,  128, 128);
    k_pack<<<24, 256, 0, stream>>>(W3,  W3p,  128, 384);
    k_pack<<<8,  256, 0, stream>>>(U,   Upk,  128, 128);
    k_pack<<<8,  256, 0, stream>>>(V,   Vpk,  128, 128);
    k_pack<<<16, 256, 0, stream>>>(Wu1, Wu1p, 256, 128);
    k_pack<<<24, 256, 0, stream>>>(Wu2, Wu2p, 128, 384);

    k_zero_ints<<<(N_NODES + 255) / 256,        256, 0, stream>>>(cnt, N_NODES);
    k_fill     <<<(N_EDGES + 255) / 256,        256, 0, stream>>>(ei, cnt, slot);
    k_basis    <<<(N_EDGES * NRBF + 255) / 256, 256, 0, stream>>>(ea2, basis);

    k_A_mfma   <<<N_NODES / 16, 256, 0, stream>>>(x, W1p, b1, W3p, b3, P1);
    k_gather1  <<<N_NODES,      128, 0, stream>>>(x, P1, basis, ea1, W2, b2, cnt, slot, out);
    k_B_mfma   <<<N_NODES / 16, 256, 0, stream>>>(Upk, Vpk, Wu1p, bu1, Wu2p, bu2, out, M2);
    k_gather2  <<<N_NODES,      256, 0, stream>>>(M2, cnt, slot, out);
}